// Round 5
// baseline (430.448 us; speedup 1.0000x reference)
//
#include <hip/hip_runtime.h>
#include <hip/hip_bf16.h>

typedef __attribute__((ext_vector_type(8))) short bf16x8;
typedef __attribute__((ext_vector_type(4))) short s16x4;
typedef __attribute__((ext_vector_type(4))) float f32x4;
typedef __attribute__((ext_vector_type(4))) float float4v;

static __device__ __forceinline__ unsigned short f2b(float f) {
  unsigned int u = __builtin_bit_cast(unsigned int, f);
  u += 0x7fffu + ((u >> 16) & 1u);
  return (unsigned short)(u >> 16);
}
static __device__ __forceinline__ float b2f(unsigned short s) {
  unsigned int u = ((unsigned int)s) << 16;
  return __builtin_bit_cast(float, u);
}
static __device__ __forceinline__ float siluf(float x) {
  return x / (1.f + expf(-x));
}
// async global->LDS, 16B/lane; LDS dest = wave-uniform base + lane*16
static __device__ __forceinline__ void gl16(const void* g, void* l) {
  __builtin_amdgcn_global_load_lds(
      (const __attribute__((address_space(1))) unsigned int*)g,
      (__attribute__((address_space(3))) unsigned int*)l, 16, 0, 0);
}
template <int N>
static __device__ __forceinline__ void waitv() {
  if constexpr (N == 0) asm volatile("s_waitcnt vmcnt(0)" ::: "memory");
  else if constexpr (N == 2) asm volatile("s_waitcnt vmcnt(2)" ::: "memory");
  else if constexpr (N == 4) asm volatile("s_waitcnt vmcnt(4)" ::: "memory");
  else if constexpr (N == 8) asm volatile("s_waitcnt vmcnt(8)" ::: "memory");
}

// ---------------------------------------------------------------------------
// Deep-pipelined bf16 GEMM: C[M,N] = A[M,K] @ W[N,K]^T, fp32 accum.
// TM x TN tile, BK=32, 4 waves (2x2). DEPTH-4 LDS ring, stage tile t+2 at
// loop top, counted s_waitcnt vmcnt(2*LPT) + raw s_barrier (ONE per iter,
// never vmcnt(0) mid-loop) -- T3/T4. LDS chunk XOR-swizzle applied on BOTH
// sides (pre-swizzled global source for global_load_lds + swizzled ds_read,
// rule #21). 1-D grid with bijective XCD swizzle, bn-fastest (T1).
// MODE 0: v += bias[n]; fp32 of[] + bf16 ob[]                          (pre)
// MODE 1: n<512: silu(v*cw3+cb)->ob (xi); else silu(v)->ob2 (sz)        (xz)
// MODE 2: v += of[]; write back of[] + bf16 ob[]                  (out_proj)
// MODE 3: plain fp32 store to of[]                                    (xdbl)
// ---------------------------------------------------------------------------
template <int MODE, int TM, int TN>
__global__ __launch_bounds__(256) void gemm_pl(
    const unsigned short* __restrict__ A, const unsigned short* __restrict__ W,
    int N, int K, int GY,
    const float* __restrict__ p0, const float* __restrict__ p1,
    float* __restrict__ of, unsigned short* __restrict__ ob,
    unsigned short* __restrict__ ob2) {
  constexpr int FM = TM / 32, FN = TN / 32;
  constexpr int IA = TM / 64;  // A gl16 instrs per wave per tile
  constexpr int IW = TN / 64;  // W gl16 instrs per wave per tile
  constexpr int LPT = IA + IW;
  __shared__ __align__(16) unsigned short As[4][TM * 32];
  __shared__ __align__(16) unsigned short Ws[4][TN * 32];

  const int t = threadIdx.x, lane = t & 63, wave = t >> 6;
  const int lr = lane & 15;
  // bijective XCD swizzle (all grids divisible by 8), bn-fastest for A reuse
  const int q = gridDim.x >> 3;
  const int s = (blockIdx.x & 7) * q + (blockIdx.x >> 3);
  const int bm = (s / GY) * TM, bn = (s % GY) * TN;
  const int wr = (wave >> 1) * (TM / 2), wc = (wave & 1) * (TN / 2);

  f32x4 acc[FM][FN];
#pragma unroll
  for (int i = 0; i < FM; ++i)
#pragma unroll
    for (int j = 0; j < FN; ++j) acc[i][j] = (f32x4){0.f, 0.f, 0.f, 0.f};

  // staging source pointers (global pre-swizzled to match LDS layout;
  // 16-row chunk: lane l -> row (l>>2), stored k-chunk (l&3) holds logical
  // chunk (l&3)^((row>>1)&3))
  const unsigned short* agB =
      A + (long)(bm + wave * (TM / 4) + (lane >> 2)) * K +
      ((lane & 3) ^ ((lane >> 3) & 3)) * 8;
  const unsigned short* wgB =
      W + (long)(bn + wave * (TN / 4) + (lane >> 2)) * K +
      ((lane & 3) ^ ((lane >> 3) & 3)) * 8;

  auto STAGE = [&](int k0, int b) {  // k0 in elements
#pragma unroll
    for (int j = 0; j < IA; ++j)
      gl16(agB + k0 + (long)j * 16 * K, &As[b][(wave * (TM / 4) + j * 16) * 32]);
#pragma unroll
    for (int j = 0; j < IW; ++j)
      gl16(wgB + k0 + (long)j * 16 * K, &Ws[b][(wave * (TN / 4) + j * 16) * 32]);
  };

  auto COMPUTE = [&](int b) {
    bf16x8 af[FM], bg[FN];
    const int sw = ((lane >> 4) ^ ((lane >> 1) & 3)) * 8;  // swizzled read off
#pragma unroll
    for (int m = 0; m < FM; ++m)
      af[m] = *(const bf16x8*)&As[b][(wr + m * 16 + lr) * 32 + sw];
#pragma unroll
    for (int n = 0; n < FN; ++n)
      bg[n] = *(const bf16x8*)&Ws[b][(wc + n * 16 + lr) * 32 + sw];
#pragma unroll
    for (int m = 0; m < FM; ++m)
#pragma unroll
      for (int n = 0; n < FN; ++n)
        acc[m][n] = __builtin_amdgcn_mfma_f32_16x16x32_bf16(af[m], bg[n],
                                                            acc[m][n], 0, 0, 0);
  };

  const int NT = K >> 5;  // always >= 2 here
  STAGE(0, 0);
  STAGE(32, 1);
  for (int tt = 0; tt < NT; ++tt) {
    if (tt + 2 < NT) {
      STAGE((tt + 2) << 5, (tt + 2) & 3);
      waitv<2 * LPT>();
    } else if (tt + 1 < NT) {
      waitv<LPT>();
    } else {
      waitv<0>();
    }
    __builtin_amdgcn_s_barrier();
    COMPUTE(tt & 3);
    __builtin_amdgcn_sched_barrier(0);
  }

  // C/D layout (m89): col = lane&15, row = (lane>>4)*4 + reg
  const int m0 = bm + wr + (lane >> 4) * 4;
  const int n0 = bn + wc + lr;
#pragma unroll
  for (int mi = 0; mi < FM; ++mi)
#pragma unroll
    for (int ni = 0; ni < FN; ++ni) {
      const int n = n0 + ni * 16;
#pragma unroll
      for (int r = 0; r < 4; ++r) {
        const int m = m0 + mi * 16 + r;
        float v = acc[mi][ni][r];
        if constexpr (MODE == 0) {
          v += p0[n];
          of[(long)m * N + n] = v;
          ob[(long)m * N + n] = f2b(v);
        } else if constexpr (MODE == 1) {
          if (n < 512) {
            float u = v * p0[n * 4 + 3] + p1[n];  // conv tap 3 + bias (L=1)
            ob[(long)m * 512 + n] = f2b(siluf(u));
          } else {
            ob2[(long)m * 512 + (n - 512)] = f2b(siluf(v));
          }
        } else if constexpr (MODE == 2) {
          float nv = of[(long)m * N + n] + v;
          of[(long)m * N + n] = nv;
          ob[(long)m * N + n] = f2b(nv);
        } else {
          of[(long)m * N + n] = v;
        }
      }
    }
}

// x fp32 -> bf16 streaming cast (8192*2048 elems)
__global__ __launch_bounds__(256) void castx(const float* __restrict__ s,
                                             unsigned short* __restrict__ d) {
  const int n4 = (8192 * 2048) / 4;
  for (int i = blockIdx.x * 256 + threadIdx.x; i < n4; i += gridDim.x * 256) {
    float4v v = ((const float4v*)s)[i];
    s16x4 o;
    o[0] = (short)f2b(v[0]); o[1] = (short)f2b(v[1]);
    o[2] = (short)f2b(v[2]); o[3] = (short)f2b(v[3]);
    ((s16x4*)d)[i] = o;
  }
}

// merged weight precast: W_pre, in_w, out_w -> bf16; x_proj -> padded 64-row bf16
__global__ __launch_bounds__(256) void precast(
    const float* __restrict__ wpre, const float* __restrict__ inw,
    const float* __restrict__ ow, const float* __restrict__ xw,
    unsigned short* __restrict__ wpreb, unsigned short* __restrict__ inwb,
    unsigned short* __restrict__ owb, unsigned short* __restrict__ xwpb) {
  const int S0 = 524288;        // 256*2048
  const int S1 = S0 + 1310720;  // + 5*1024*256
  const int S2 = S1 + 655360;   // + 5*256*512
  const int S3 = S2 + 163840;   // + 5*64*512
  int i4 = (blockIdx.x * 256 + threadIdx.x) * 4;
  if (i4 >= S3) return;
  float4v v = {0.f, 0.f, 0.f, 0.f};
  unsigned short* dst;
  if (i4 < S0) {
    v = *(const float4v*)(wpre + i4);
    dst = wpreb + i4;
  } else if (i4 < S1) {
    int o = i4 - S0;
    v = *(const float4v*)(inw + o);
    dst = inwb + o;
  } else if (i4 < S2) {
    int o = i4 - S1;
    v = *(const float4v*)(ow + o);
    dst = owb + o;
  } else {
    int o = i4 - S2;
    dst = xwpb + o;
    int k = o & 511, j = (o >> 9) & 63, b = o >> 15;
    if (j < 48) v = *(const float4v*)(xw + ((long)(b * 48 + j)) * 512 + k);
  }
  s16x4 sv;
  sv[0] = (short)f2b(v[0]); sv[1] = (short)f2b(v[1]);
  sv[2] = (short)f2b(v[2]); sv[3] = (short)f2b(v[3]);
  *(s16x4*)dst = sv;
}

// Per-row: dt = softplus(dtw @ xdbl[:16] + dtb); BC = dot(xdbl[16:32],xdbl[32:48])
// y = xi * (dt*BC + D) * silu(z)   (L=1 collapses the scan to this)
// thread t: 4 consecutive d = (t&127)*4; row group g = t>>7 (rows r0+g, step 2)
__global__ __launch_bounds__(256) void small_ops(
    const float* __restrict__ xdbl, const float* __restrict__ dtw,
    const float* __restrict__ dtb, const float* __restrict__ Dp,
    const unsigned short* __restrict__ xi, const unsigned short* __restrict__ sz,
    unsigned short* __restrict__ yb) {
  const int t = threadIdx.x;
  const int dq = (t & 127) * 4;
  const int g = t >> 7;
  float wreg[4][16], bias[4], Dv[4];
#pragma unroll
  for (int j = 0; j < 4; ++j) {
    bias[j] = dtb[dq + j];
    Dv[j] = Dp[dq + j];
#pragma unroll
    for (int i = 0; i < 16; ++i) wreg[j][i] = dtw[(dq + j) * 16 + i];
  }
  const int r0 = blockIdx.x * 32 + g;
  for (int rr = 0; rr < 16; ++rr) {
    const int r = r0 + rr * 2;
    const float* xr = xdbl + (long)r * 64;
    float dtr[16];
#pragma unroll
    for (int i = 0; i < 16; ++i) dtr[i] = xr[i];
    float BC = 0.f;
#pragma unroll
    for (int ss = 0; ss < 16; ++ss) BC += xr[16 + ss] * xr[32 + ss];
    s16x4 xv = *(const s16x4*)&xi[(long)r * 512 + dq];
    s16x4 zv = *(const s16x4*)&sz[(long)r * 512 + dq];
    s16x4 yo;
#pragma unroll
    for (int j = 0; j < 4; ++j) {
      float a = bias[j];
#pragma unroll
      for (int i = 0; i < 16; ++i) a += wreg[j][i] * dtr[i];
      const float dtv = (a > 20.f) ? a : log1pf(expf(a));
      const float y = b2f((unsigned short)xv[j]) * (dtv * BC + Dv[j]) *
                      b2f((unsigned short)zv[j]);
      yo[j] = (short)f2b(y);
    }
    *(s16x4*)&yb[(long)r * 512 + dq] = yo;
  }
}

// LayerNorm(256) + classifier (8 outputs). One wave per row.
__global__ __launch_bounds__(256) void final_ln_cls(
    const float* __restrict__ h, const float* __restrict__ g,
    const float* __restrict__ be, const float* __restrict__ Wc,
    const float* __restrict__ bc, float* __restrict__ out) {
  const int wave = threadIdx.x >> 6, lane = threadIdx.x & 63;
  const int row = blockIdx.x * 4 + wave;
  const float4v* hr = (const float4v*)(h + (long)row * 256);
  float4v v = hr[lane];
  float s = v[0] + v[1] + v[2] + v[3];
#pragma unroll
  for (int o = 32; o; o >>= 1) s += __shfl_xor(s, o);
  const float mu = s * (1.f / 256.f);
  float d0 = v[0] - mu, d1 = v[1] - mu, d2 = v[2] - mu, d3 = v[3] - mu;
  float qq = d0 * d0 + d1 * d1 + d2 * d2 + d3 * d3;
#pragma unroll
  for (int o = 32; o; o >>= 1) qq += __shfl_xor(qq, o);
  const float rs = rsqrtf(qq * (1.f / 256.f) + 1e-5f);
  const float4v gv = ((const float4v*)g)[lane];
  const float4v bv = ((const float4v*)be)[lane];
  float hn[4];
  hn[0] = d0 * rs * gv[0] + bv[0];
  hn[1] = d1 * rs * gv[1] + bv[1];
  hn[2] = d2 * rs * gv[2] + bv[2];
  hn[3] = d3 * rs * gv[3] + bv[3];
  float lg[8];
#pragma unroll
  for (int o = 0; o < 8; ++o) {
    const float4v wv = ((const float4v*)(Wc + o * 256))[lane];
    float p = hn[0] * wv[0] + hn[1] * wv[1] + hn[2] * wv[2] + hn[3] * wv[3];
#pragma unroll
    for (int x = 32; x; x >>= 1) p += __shfl_xor(p, x);
    lg[o] = p;
  }
  if (lane == 0) {
#pragma unroll
    for (int o = 0; o < 8; ++o) out[(long)row * 8 + o] = lg[o] + bc[o];
  }
}

extern "C" void kernel_launch(void* const* d_in, const int* in_sizes, int n_in,
                              void* d_out, int out_size, void* d_ws,
                              size_t ws_size, hipStream_t stream) {
  const float* x      = (const float*)d_in[0];
  const float* W_pre  = (const float*)d_in[1];
  const float* b_pre  = (const float*)d_in[2];
  const float* in_w   = (const float*)d_in[3];
  const float* conv_w = (const float*)d_in[4];
  const float* conv_b = (const float*)d_in[5];
  const float* x_w    = (const float*)d_in[6];
  const float* dt_w   = (const float*)d_in[7];
  const float* dt_b   = (const float*)d_in[8];
  // d_in[9] = A_log: dead (scan starts from h0=0 and L=1)
  const float* Dp     = (const float*)d_in[10];
  const float* out_w  = (const float*)d_in[11];
  const float* ln_g   = (const float*)d_in[12];
  const float* ln_b   = (const float*)d_in[13];
  const float* W_cls  = (const float*)d_in[14];
  const float* b_cls  = (const float*)d_in[15];
  float* out = (float*)d_out;

  char* w = (char*)d_ws;
  unsigned short* wpreb = (unsigned short*)w; w += 256 * 2048 * 2;
  unsigned short* inwb  = (unsigned short*)w; w += 5 * 1024 * 256 * 2;
  unsigned short* xwpb  = (unsigned short*)w; w += 5 * 64 * 512 * 2;
  unsigned short* owb   = (unsigned short*)w; w += 5 * 256 * 512 * 2;
  float*          h     = (float*)w;          w += 8192 * 256 * 4;
  unsigned short* hb    = (unsigned short*)w; w += 8192 * 256 * 2;
  // 32MB union: xb (bf16 x, live castx->pre) overlays xib/szb/yb/xdbl
  // (live only from in_proj onward)
  unsigned short* xb    = (unsigned short*)w;
  unsigned short* xib   = (unsigned short*)w; w += 8192 * 512 * 2;
  unsigned short* szb   = (unsigned short*)w; w += 8192 * 512 * 2;
  unsigned short* yb    = (unsigned short*)w; w += 8192 * 512 * 2;
  float*          xdbl  = (float*)w;          w += 8192 * 64 * 4;
  w += 8192 * 2048 * 2 - (8192 * 512 * 2) * 3 - 8192 * 64 * 4;  // union tail

  precast<<<2592, 256, 0, stream>>>(W_pre, in_w, out_w, x_w,
                                    wpreb, inwb, owb, xwpb);
  castx<<<2048, 256, 0, stream>>>(x, xb);

  // h = x @ W_pre^T + b_pre
  gemm_pl<0, 64, 64><<<512, 256, 0, stream>>>(
      xb, wpreb, 256, 2048, 4, b_pre, nullptr, h, hb, nullptr);

  for (int blk = 0; blk < 5; ++blk) {
    // xz = h @ in_w^T ; xi = silu(xz[:512]*cw3+cb) ; sz = silu(xz[512:])
    gemm_pl<1, 128, 128><<<512, 256, 0, stream>>>(
        hb, inwb + blk * 1024 * 256, 1024, 256, 8,
        conv_w + blk * 512 * 4, conv_b + blk * 512, nullptr, xib, szb);
    // xdbl = xi @ x_w^T (N padded 48->64)
    gemm_pl<3, 64, 64><<<128, 256, 0, stream>>>(
        xib, xwpb + blk * 64 * 512, 64, 512, 1,
        nullptr, nullptr, xdbl, nullptr, nullptr);
    // dt/BC/y elementwise
    small_ops<<<256, 256, 0, stream>>>(
        xdbl, dt_w + blk * 512 * 16, dt_b + blk * 512, Dp + blk * 512,
        xib, szb, yb);
    // h += y @ out_w^T
    gemm_pl<2, 64, 64><<<512, 256, 0, stream>>>(
        yb, owb + blk * 256 * 512, 256, 512, 4,
        nullptr, nullptr, h, hb, nullptr);
  }

  final_ln_cls<<<2048, 256, 0, stream>>>(h, ln_g, ln_b, W_cls, b_cls, out);
}

// Round 6
// 414.702 us; speedup vs baseline: 1.0380x; 1.0380x over previous
//
#include <hip/hip_runtime.h>
#include <hip/hip_bf16.h>

typedef __attribute__((ext_vector_type(8))) short bf16x8;
typedef __attribute__((ext_vector_type(4))) short s16x4;
typedef __attribute__((ext_vector_type(4))) float f32x4;
typedef __attribute__((ext_vector_type(4))) float float4v;

static __device__ __forceinline__ unsigned short f2b(float f) {
  unsigned int u = __builtin_bit_cast(unsigned int, f);
  u += 0x7fffu + ((u >> 16) & 1u);
  return (unsigned short)(u >> 16);
}
static __device__ __forceinline__ float b2f(unsigned short s) {
  unsigned int u = ((unsigned int)s) << 16;
  return __builtin_bit_cast(float, u);
}
static __device__ __forceinline__ float siluf(float x) {
  return x / (1.f + expf(-x));
}
// async global->LDS, 16B/lane; LDS dest wave-uniform base + lane*16,
// global source per-lane (enables source-side swizzling, rule #21)
static __device__ __forceinline__ void gl16(const void* g, void* l) {
  __builtin_amdgcn_global_load_lds(
      (const __attribute__((address_space(1))) unsigned int*)g,
      (__attribute__((address_space(3))) unsigned int*)l, 16, 0, 0);
}
template <int N>
static __device__ __forceinline__ void waitv() {
  if constexpr (N == 0) asm volatile("s_waitcnt vmcnt(0)" ::: "memory");
  else if constexpr (N == 2) asm volatile("s_waitcnt vmcnt(2)" ::: "memory");
  else if constexpr (N == 3) asm volatile("s_waitcnt vmcnt(3)" ::: "memory");
  else if constexpr (N == 4) asm volatile("s_waitcnt vmcnt(4)" ::: "memory");
  else if constexpr (N == 6) asm volatile("s_waitcnt vmcnt(6)" ::: "memory");
  else if constexpr (N == 8) asm volatile("s_waitcnt vmcnt(8)" ::: "memory");
}

// ---------------------------------------------------------------------------
// Deep-pipelined bf16 GEMM: C[M,N] = A[M,K] @ W[N,K]^T, fp32 accum.
// TM x TN tile, BK=32, 4 waves (2x2). DEPTH-4 LDS ring, stage tile t+2 at
// loop top, counted s_waitcnt vmcnt(2*LPT) + raw s_barrier (never vmcnt(0)
// mid-loop) -- T3/T4. Chunk XOR-swizzle both-sides (pre-swizzled global
// source + swizzled ds_read). Bijective XCD swizzle, bn-fastest (T1).
// T5 setprio around MFMA cluster.
// MODE 0: v += bias[n]; fp32 of[] + bf16 ob[]                          (pre)
// MODE 1: n<512: silu(v*cw3+cb)->ob (xi); else silu(v)->ob2 (sz)        (xz)
// MODE 2: v += of[]; write back of[] + bf16 ob[]                  (out_proj)
// ---------------------------------------------------------------------------
template <int MODE, int TM, int TN>
__global__ __launch_bounds__(256) void gemm_pl(
    const unsigned short* __restrict__ A, const unsigned short* __restrict__ W,
    int N, int K, int GY,
    const float* __restrict__ p0, const float* __restrict__ p1,
    float* __restrict__ of, unsigned short* __restrict__ ob,
    unsigned short* __restrict__ ob2) {
  constexpr int FM = TM / 32, FN = TN / 32;
  constexpr int IA = TM / 64, IW = TN / 64;
  constexpr int LPT = IA + IW;
  __shared__ __align__(16) unsigned short As[4][TM * 32];
  __shared__ __align__(16) unsigned short Ws[4][TN * 32];

  const int t = threadIdx.x, lane = t & 63, wave = t >> 6;
  const int lr = lane & 15;
  const int q = gridDim.x >> 3;
  const int s = (blockIdx.x & 7) * q + (blockIdx.x >> 3);
  const int bm = (s / GY) * TM, bn = (s % GY) * TN;
  const int wr = (wave >> 1) * (TM / 2), wc = (wave & 1) * (TN / 2);

  f32x4 acc[FM][FN];
#pragma unroll
  for (int i = 0; i < FM; ++i)
#pragma unroll
    for (int j = 0; j < FN; ++j) acc[i][j] = (f32x4){0.f, 0.f, 0.f, 0.f};

  const unsigned short* agB =
      A + (long)(bm + wave * (TM / 4) + (lane >> 2)) * K +
      ((lane & 3) ^ ((lane >> 3) & 3)) * 8;
  const unsigned short* wgB =
      W + (long)(bn + wave * (TN / 4) + (lane >> 2)) * K +
      ((lane & 3) ^ ((lane >> 3) & 3)) * 8;

  auto STAGE = [&](int k0, int b) {
#pragma unroll
    for (int j = 0; j < IA; ++j)
      gl16(agB + k0 + (long)j * 16 * K, &As[b][(wave * (TM / 4) + j * 16) * 32]);
#pragma unroll
    for (int j = 0; j < IW; ++j)
      gl16(wgB + k0 + (long)j * 16 * K, &Ws[b][(wave * (TN / 4) + j * 16) * 32]);
  };

  auto COMPUTE = [&](int b) {
    bf16x8 af[FM], bg[FN];
    const int sw = ((lane >> 4) ^ ((lane >> 1) & 3)) * 8;
#pragma unroll
    for (int m = 0; m < FM; ++m)
      af[m] = *(const bf16x8*)&As[b][(wr + m * 16 + lr) * 32 + sw];
#pragma unroll
    for (int n = 0; n < FN; ++n)
      bg[n] = *(const bf16x8*)&Ws[b][(wc + n * 16 + lr) * 32 + sw];
    __builtin_amdgcn_s_setprio(1);
#pragma unroll
    for (int m = 0; m < FM; ++m)
#pragma unroll
      for (int n = 0; n < FN; ++n)
        acc[m][n] = __builtin_amdgcn_mfma_f32_16x16x32_bf16(af[m], bg[n],
                                                            acc[m][n], 0, 0, 0);
    __builtin_amdgcn_s_setprio(0);
  };

  const int NT = K >> 5;
  STAGE(0, 0);
  STAGE(32, 1);
  for (int tt = 0; tt < NT; ++tt) {
    if (tt + 2 < NT) {
      STAGE((tt + 2) << 5, (tt + 2) & 3);
      waitv<2 * LPT>();
    } else if (tt + 1 < NT) {
      waitv<LPT>();
    } else {
      waitv<0>();
    }
    __builtin_amdgcn_s_barrier();
    COMPUTE(tt & 3);
    __builtin_amdgcn_sched_barrier(0);
  }

  // C/D layout (m89): col = lane&15, row = (lane>>4)*4 + reg
  const int m0 = bm + wr + (lane >> 4) * 4;
  const int n0 = bn + wc + lr;
#pragma unroll
  for (int mi = 0; mi < FM; ++mi)
#pragma unroll
    for (int ni = 0; ni < FN; ++ni) {
      const int n = n0 + ni * 16;
#pragma unroll
      for (int r = 0; r < 4; ++r) {
        const int m = m0 + mi * 16 + r;
        float v = acc[mi][ni][r];
        if constexpr (MODE == 0) {
          v += p0[n];
          of[(long)m * N + n] = v;
          ob[(long)m * N + n] = f2b(v);
        } else if constexpr (MODE == 1) {
          if (n < 512) {
            float u = v * p0[n * 4 + 3] + p1[n];  // conv tap 3 + bias (L=1)
            ob[(long)m * 512 + n] = f2b(siluf(u));
          } else {
            ob2[(long)m * 512 + (n - 512)] = f2b(siluf(v));
          }
        } else if constexpr (MODE == 2) {
          float nv = of[(long)m * N + n] + v;
          of[(long)m * N + n] = nv;
          ob[(long)m * N + n] = f2b(nv);
        }
      }
    }
}

// ---------------------------------------------------------------------------
// Fused xdbl GEMM + SSM elementwise (replaces xdbl gemm + small_ops).
// Block = 32 rows. LDS: xi 32x512 bf16 + W 64x512 bf16 (both per-row
// chunk-XOR swizzled, staged via gl16 one row per instr) + xdbl 32x64 f32.
// Phase 1: xdbl[32,64] = xi @ xwp^T via MFMA (K=512).
// Phase 2: dt = softplus(dtw@xdbl[:,:16]+dtb); BC = dot(xdbl[:,16:32],
//          xdbl[:,32:48]); y = xi*(dt*BC+D)*silu(sz)   (L=1 scan collapse)
// ---------------------------------------------------------------------------
__global__ __launch_bounds__(256) void ssm_fuse(
    const unsigned short* __restrict__ xi_g, const unsigned short* __restrict__ xwp,
    const unsigned short* __restrict__ sz_g, const float* __restrict__ dtw,
    const float* __restrict__ dtb, const float* __restrict__ Dp,
    unsigned short* __restrict__ yb) {
  __shared__ __align__(16) unsigned short Xl[32 * 512];
  __shared__ __align__(16) unsigned short Wl[64 * 512];
  __shared__ __align__(16) float Dxl[32 * 64];
  const int t = threadIdx.x, lane = t & 63, wave = t >> 6;
  const int bm = blockIdx.x * 32;
  const int lr = lane & 15;

  // stage: one gl16 per row (64 lanes x 16B = 1KB = one 512-elem bf16 row);
  // stored chunk l holds logical chunk l ^ (row&7)
#pragma unroll
  for (int j = 0; j < 8; ++j) {
    const int r = wave * 8 + j;
    gl16(xi_g + (long)(bm + r) * 512 + (lane ^ (r & 7)) * 8, &Xl[r * 512]);
  }
#pragma unroll
  for (int j = 0; j < 16; ++j) {
    const int r = wave * 16 + j;
    gl16(xwp + (long)r * 512 + (lane ^ (r & 7)) * 8, &Wl[r * 512]);
  }
  waitv<0>();
  __builtin_amdgcn_s_barrier();

  // MFMA: 32x64 output, waves 2x2 -> wave 16x32 (FM=1, FN=2)
  const int wr = (wave >> 1) * 16, wc = (wave & 1) * 32;
  f32x4 acc[2] = {(f32x4){0.f, 0.f, 0.f, 0.f}, (f32x4){0.f, 0.f, 0.f, 0.f}};
  const int ra = wr + lr;
#pragma unroll
  for (int ks = 0; ks < 16; ++ks) {
    const int c0 = ks * 4 + (lane >> 4);
    bf16x8 af = *(const bf16x8*)&Xl[ra * 512 + (c0 ^ (ra & 7)) * 8];
#pragma unroll
    for (int n = 0; n < 2; ++n) {
      const int rb = wc + n * 16 + lr;
      bf16x8 bg = *(const bf16x8*)&Wl[rb * 512 + (c0 ^ (rb & 7)) * 8];
      acc[n] = __builtin_amdgcn_mfma_f32_16x16x32_bf16(af, bg, acc[n], 0, 0, 0);
    }
  }
  // write xdbl to LDS (C/D: col=lane&15, row=(lane>>4)*4+r)
  const int m0 = wr + (lane >> 4) * 4;
#pragma unroll
  for (int n = 0; n < 2; ++n)
#pragma unroll
    for (int r = 0; r < 4; ++r)
      Dxl[(m0 + r) * 64 + wc + n * 16 + lr] = acc[n][r];
  __syncthreads();

  // epilogue: thread owns 4 consecutive d = (t&127)*4, rows of parity t>>7
  const int dq = (t & 127) * 4;
  const int g = t >> 7;
  float wreg[4][16], bias[4], Dv[4];
#pragma unroll
  for (int j = 0; j < 4; ++j) {
    bias[j] = dtb[dq + j];
    Dv[j] = Dp[dq + j];
#pragma unroll
    for (int i = 0; i < 16; ++i) wreg[j][i] = dtw[(dq + j) * 16 + i];
  }
  const int lc = dq >> 3, lo = dq & 7;
  for (int rr = 0; rr < 16; ++rr) {
    const int r = g + rr * 2;
    const float* xr = &Dxl[r * 64];
    float dtr[16];
#pragma unroll
    for (int i = 0; i < 16; ++i) dtr[i] = xr[i];
    float BC = 0.f;
#pragma unroll
    for (int ss = 0; ss < 16; ++ss) BC += xr[16 + ss] * xr[32 + ss];
    s16x4 xv = *(const s16x4*)&Xl[r * 512 + (lc ^ (r & 7)) * 8 + lo];
    s16x4 zv = *(const s16x4*)&sz_g[(long)(bm + r) * 512 + dq];
    s16x4 yo;
#pragma unroll
    for (int j = 0; j < 4; ++j) {
      float a = bias[j];
#pragma unroll
      for (int i = 0; i < 16; ++i) a += wreg[j][i] * dtr[i];
      const float dtv = (a > 20.f) ? a : log1pf(expf(a));
      const float y = b2f((unsigned short)xv[j]) * (dtv * BC + Dv[j]) *
                      b2f((unsigned short)zv[j]);
      yo[j] = (short)f2b(y);
    }
    *(s16x4*)&yb[(long)(bm + r) * 512 + dq] = yo;
  }
}

// x fp32 -> bf16 streaming cast (8192*2048 elems)
__global__ __launch_bounds__(256) void castx(const float* __restrict__ s,
                                             unsigned short* __restrict__ d) {
  const int n4 = (8192 * 2048) / 4;
  for (int i = blockIdx.x * 256 + threadIdx.x; i < n4; i += gridDim.x * 256) {
    float4v v = ((const float4v*)s)[i];
    s16x4 o;
    o[0] = (short)f2b(v[0]); o[1] = (short)f2b(v[1]);
    o[2] = (short)f2b(v[2]); o[3] = (short)f2b(v[3]);
    ((s16x4*)d)[i] = o;
  }
}

// merged weight precast: W_pre, in_w, out_w -> bf16; x_proj -> padded 64-row bf16
__global__ __launch_bounds__(256) void precast(
    const float* __restrict__ wpre, const float* __restrict__ inw,
    const float* __restrict__ ow, const float* __restrict__ xw,
    unsigned short* __restrict__ wpreb, unsigned short* __restrict__ inwb,
    unsigned short* __restrict__ owb, unsigned short* __restrict__ xwpb) {
  const int S0 = 524288;        // 256*2048
  const int S1 = S0 + 1310720;  // + 5*1024*256
  const int S2 = S1 + 655360;   // + 5*256*512
  const int S3 = S2 + 163840;   // + 5*64*512
  int i4 = (blockIdx.x * 256 + threadIdx.x) * 4;
  if (i4 >= S3) return;
  float4v v = {0.f, 0.f, 0.f, 0.f};
  unsigned short* dst;
  if (i4 < S0) {
    v = *(const float4v*)(wpre + i4);
    dst = wpreb + i4;
  } else if (i4 < S1) {
    int o = i4 - S0;
    v = *(const float4v*)(inw + o);
    dst = inwb + o;
  } else if (i4 < S2) {
    int o = i4 - S1;
    v = *(const float4v*)(ow + o);
    dst = owb + o;
  } else {
    int o = i4 - S2;
    dst = xwpb + o;
    int k = o & 511, j = (o >> 9) & 63, b = o >> 15;
    if (j < 48) v = *(const float4v*)(xw + ((long)(b * 48 + j)) * 512 + k);
  }
  s16x4 sv;
  sv[0] = (short)f2b(v[0]); sv[1] = (short)f2b(v[1]);
  sv[2] = (short)f2b(v[2]); sv[3] = (short)f2b(v[3]);
  *(s16x4*)dst = sv;
}

// LayerNorm(256) + classifier (8 outputs). One wave per row.
__global__ __launch_bounds__(256) void final_ln_cls(
    const float* __restrict__ h, const float* __restrict__ g,
    const float* __restrict__ be, const float* __restrict__ Wc,
    const float* __restrict__ bc, float* __restrict__ out) {
  const int wave = threadIdx.x >> 6, lane = threadIdx.x & 63;
  const int row = blockIdx.x * 4 + wave;
  const float4v* hr = (const float4v*)(h + (long)row * 256);
  float4v v = hr[lane];
  float s = v[0] + v[1] + v[2] + v[3];
#pragma unroll
  for (int o = 32; o; o >>= 1) s += __shfl_xor(s, o);
  const float mu = s * (1.f / 256.f);
  float d0 = v[0] - mu, d1 = v[1] - mu, d2 = v[2] - mu, d3 = v[3] - mu;
  float qq = d0 * d0 + d1 * d1 + d2 * d2 + d3 * d3;
#pragma unroll
  for (int o = 32; o; o >>= 1) qq += __shfl_xor(qq, o);
  const float rs = rsqrtf(qq * (1.f / 256.f) + 1e-5f);
  const float4v gv = ((const float4v*)g)[lane];
  const float4v bv = ((const float4v*)be)[lane];
  float hn[4];
  hn[0] = d0 * rs * gv[0] + bv[0];
  hn[1] = d1 * rs * gv[1] + bv[1];
  hn[2] = d2 * rs * gv[2] + bv[2];
  hn[3] = d3 * rs * gv[3] + bv[3];
  float lg[8];
#pragma unroll
  for (int o = 0; o < 8; ++o) {
    const float4v wv = ((const float4v*)(Wc + o * 256))[lane];
    float p = hn[0] * wv[0] + hn[1] * wv[1] + hn[2] * wv[2] + hn[3] * wv[3];
#pragma unroll
    for (int x = 32; x; x >>= 1) p += __shfl_xor(p, x);
    lg[o] = p;
  }
  if (lane == 0) {
#pragma unroll
    for (int o = 0; o < 8; ++o) out[(long)row * 8 + o] = lg[o] + bc[o];
  }
}

extern "C" void kernel_launch(void* const* d_in, const int* in_sizes, int n_in,
                              void* d_out, int out_size, void* d_ws,
                              size_t ws_size, hipStream_t stream) {
  const float* x      = (const float*)d_in[0];
  const float* W_pre  = (const float*)d_in[1];
  const float* b_pre  = (const float*)d_in[2];
  const float* in_w   = (const float*)d_in[3];
  const float* conv_w = (const float*)d_in[4];
  const float* conv_b = (const float*)d_in[5];
  const float* x_w    = (const float*)d_in[6];
  const float* dt_w   = (const float*)d_in[7];
  const float* dt_b   = (const float*)d_in[8];
  // d_in[9] = A_log: dead (scan starts from h0=0 and L=1)
  const float* Dp     = (const float*)d_in[10];
  const float* out_w  = (const float*)d_in[11];
  const float* ln_g   = (const float*)d_in[12];
  const float* ln_b   = (const float*)d_in[13];
  const float* W_cls  = (const float*)d_in[14];
  const float* b_cls  = (const float*)d_in[15];
  float* out = (float*)d_out;

  char* w = (char*)d_ws;
  unsigned short* wpreb = (unsigned short*)w; w += 256 * 2048 * 2;
  unsigned short* inwb  = (unsigned short*)w; w += 5 * 1024 * 256 * 2;
  unsigned short* xwpb  = (unsigned short*)w; w += 5 * 64 * 512 * 2;
  unsigned short* owb   = (unsigned short*)w; w += 5 * 256 * 512 * 2;
  float*          h     = (float*)w;          w += 8192 * 256 * 4;
  unsigned short* hb    = (unsigned short*)w; w += 8192 * 256 * 2;
  // 32MB union: xb (bf16 x, live castx->pre) overlays xib/szb/yb
  unsigned short* xb    = (unsigned short*)w;
  unsigned short* xib   = (unsigned short*)w; w += 8192 * 512 * 2;
  unsigned short* szb   = (unsigned short*)w; w += 8192 * 512 * 2;
  unsigned short* yb    = (unsigned short*)w; w += 8192 * 512 * 2;
  w += 8192 * 2048 * 2 - (8192 * 512 * 2) * 3;  // union tail

  precast<<<2592, 256, 0, stream>>>(W_pre, in_w, out_w, x_w,
                                    wpreb, inwb, owb, xwpb);
  castx<<<2048, 256, 0, stream>>>(x, xb);

  // h = x @ W_pre^T + b_pre
  gemm_pl<0, 128, 64><<<256, 256, 0, stream>>>(
      xb, wpreb, 256, 2048, 4, b_pre, nullptr, h, hb, nullptr);

  for (int blk = 0; blk < 5; ++blk) {
    // xz = h @ in_w^T ; xi = silu(xz[:512]*cw3+cb) ; sz = silu(xz[512:])
    gemm_pl<1, 128, 128><<<512, 256, 0, stream>>>(
        hb, inwb + blk * 1024 * 256, 1024, 256, 8,
        conv_w + blk * 512 * 4, conv_b + blk * 512, nullptr, xib, szb);
    // xdbl + dt/BC/y fused
    ssm_fuse<<<256, 256, 0, stream>>>(
        xib, xwpb + blk * 64 * 512, szb, dt_w + blk * 512 * 16,
        dt_b + blk * 512, Dp + blk * 512, yb);
    // h += y @ out_w^T
    gemm_pl<2, 128, 64><<<256, 256, 0, stream>>>(
        yb, owb + blk * 256 * 512, 256, 512, 4,
        nullptr, nullptr, h, hb, nullptr);
  }

  final_ln_cls<<<2048, 256, 0, stream>>>(h, ln_g, ln_b, W_cls, b_cls, out);
}

// Round 7
// 324.705 us; speedup vs baseline: 1.3257x; 1.2772x over previous
//
#include <hip/hip_runtime.h>
#include <hip/hip_bf16.h>

typedef __attribute__((ext_vector_type(8))) short bf16x8;
typedef __attribute__((ext_vector_type(4))) short s16x4;
typedef __attribute__((ext_vector_type(4))) float f32x4;
typedef __attribute__((ext_vector_type(4))) float float4v;

static __device__ __forceinline__ unsigned short f2b(float f) {
  unsigned int u = __builtin_bit_cast(unsigned int, f);
  u += 0x7fffu + ((u >> 16) & 1u);
  return (unsigned short)(u >> 16);
}
static __device__ __forceinline__ float b2f(unsigned short s) {
  unsigned int u = ((unsigned int)s) << 16;
  return __builtin_bit_cast(float, u);
}
static __device__ __forceinline__ float siluf(float x) {
  return x / (1.f + expf(-x));
}
// async global->LDS, 16B/lane; LDS dest wave-uniform base + lane*16,
// global source per-lane (enables source-side swizzling, rule #21)
static __device__ __forceinline__ void gl16(const void* g, void* l) {
  __builtin_amdgcn_global_load_lds(
      (const __attribute__((address_space(1))) unsigned int*)g,
      (__attribute__((address_space(3))) unsigned int*)l, 16, 0, 0);
}
template <int N>
static __device__ __forceinline__ void waitv() {
  if constexpr (N == 0) asm volatile("s_waitcnt vmcnt(0)" ::: "memory");
  else if constexpr (N == 2) asm volatile("s_waitcnt vmcnt(2)" ::: "memory");
  else if constexpr (N == 3) asm volatile("s_waitcnt vmcnt(3)" ::: "memory");
  else if constexpr (N == 4) asm volatile("s_waitcnt vmcnt(4)" ::: "memory");
  else if constexpr (N == 6) asm volatile("s_waitcnt vmcnt(6)" ::: "memory");
  else if constexpr (N == 8) asm volatile("s_waitcnt vmcnt(8)" ::: "memory");
}
static __device__ __forceinline__ void lgkm_bar() {
  asm volatile("s_waitcnt lgkmcnt(0)" ::: "memory");
  __builtin_amdgcn_s_barrier();
}

// ---------------------------------------------------------------------------
// pre-GEMM (proven round-4/6 structure): C = A @ W^T, bf16 MFMA, fp32 accum.
// TM x TN, BK=32, 4 waves, depth-4 ring, counted vmcnt, chunk-XOR swizzle,
// bijective XCD swizzle. MODE 0 epilogue: v += bias; fp32 of[] + bf16 ob[].
// ---------------------------------------------------------------------------
template <int MODE, int TM, int TN>
__global__ __launch_bounds__(256) void gemm_pl(
    const unsigned short* __restrict__ A, const unsigned short* __restrict__ W,
    int N, int K, int GY,
    const float* __restrict__ p0, float* __restrict__ of,
    unsigned short* __restrict__ ob) {
  constexpr int FM = TM / 32, FN = TN / 32;
  constexpr int IA = TM / 64, IW = TN / 64;
  constexpr int LPT = IA + IW;
  __shared__ __align__(16) unsigned short As[4][TM * 32];
  __shared__ __align__(16) unsigned short Ws[4][TN * 32];

  const int t = threadIdx.x, lane = t & 63, wave = t >> 6;
  const int lr = lane & 15;
  const int q = gridDim.x >> 3;
  const int s = (blockIdx.x & 7) * q + (blockIdx.x >> 3);
  const int bm = (s / GY) * TM, bn = (s % GY) * TN;
  const int wr = (wave >> 1) * (TM / 2), wc = (wave & 1) * (TN / 2);

  f32x4 acc[FM][FN];
#pragma unroll
  for (int i = 0; i < FM; ++i)
#pragma unroll
    for (int j = 0; j < FN; ++j) acc[i][j] = (f32x4){0.f, 0.f, 0.f, 0.f};

  const unsigned short* agB =
      A + (long)(bm + wave * (TM / 4) + (lane >> 2)) * K +
      ((lane & 3) ^ ((lane >> 3) & 3)) * 8;
  const unsigned short* wgB =
      W + (long)(bn + wave * (TN / 4) + (lane >> 2)) * K +
      ((lane & 3) ^ ((lane >> 3) & 3)) * 8;

  auto STAGE = [&](int k0, int b) {
#pragma unroll
    for (int j = 0; j < IA; ++j)
      gl16(agB + k0 + (long)j * 16 * K, &As[b][(wave * (TM / 4) + j * 16) * 32]);
#pragma unroll
    for (int j = 0; j < IW; ++j)
      gl16(wgB + k0 + (long)j * 16 * K, &Ws[b][(wave * (TN / 4) + j * 16) * 32]);
  };

  auto COMPUTE = [&](int b) {
    bf16x8 af[FM], bg[FN];
    const int sw = ((lane >> 4) ^ ((lane >> 1) & 3)) * 8;
#pragma unroll
    for (int m = 0; m < FM; ++m)
      af[m] = *(const bf16x8*)&As[b][(wr + m * 16 + lr) * 32 + sw];
#pragma unroll
    for (int n = 0; n < FN; ++n)
      bg[n] = *(const bf16x8*)&Ws[b][(wc + n * 16 + lr) * 32 + sw];
    __builtin_amdgcn_s_setprio(1);
#pragma unroll
    for (int m = 0; m < FM; ++m)
#pragma unroll
      for (int n = 0; n < FN; ++n)
        acc[m][n] = __builtin_amdgcn_mfma_f32_16x16x32_bf16(af[m], bg[n],
                                                            acc[m][n], 0, 0, 0);
    __builtin_amdgcn_s_setprio(0);
  };

  const int NT = K >> 5;
  STAGE(0, 0);
  STAGE(32, 1);
  for (int tt = 0; tt < NT; ++tt) {
    if (tt + 2 < NT) {
      STAGE((tt + 2) << 5, (tt + 2) & 3);
      waitv<2 * LPT>();
    } else if (tt + 1 < NT) {
      waitv<LPT>();
    } else {
      waitv<0>();
    }
    __builtin_amdgcn_s_barrier();
    COMPUTE(tt & 3);
    __builtin_amdgcn_sched_barrier(0);
  }

  const int m0 = bm + wr + (lane >> 4) * 4;
  const int n0 = bn + wc + lr;
#pragma unroll
  for (int mi = 0; mi < FM; ++mi)
#pragma unroll
    for (int ni = 0; ni < FN; ++ni) {
      const int n = n0 + ni * 16;
#pragma unroll
      for (int r = 0; r < 4; ++r) {
        const int m = m0 + mi * 16 + r;
        float v = acc[mi][ni][r] + p0[n];
        of[(long)m * N + n] = v;
        ob[(long)m * N + n] = f2b(v);
      }
    }
}

// ---------------------------------------------------------------------------
// mamba5: the 5 Mamba blocks fused in ONE kernel. Grid 256 x 512thr,
// 32 rows/block, h resident (fp32 regs + bf16 LDS). Per block-iteration:
//   P1 in_proj (32 tiles [64Nx128K], ring4 depth2, counted vmcnt)
//   P2 xdbl = xi @ xwp^T (xwp 64KB staged whole)
//   P4 dt-GEMM (padded K=32) + y epilogue (y overwrites xi in LDS)
//   P5 out_proj (8 tiles [64Nx256K], ring2 stage-after-barrier) + residual
// All LDS frag reads chunk-XOR swizzled (pos p holds global chunk p^(row&7)).
// L=1 collapse: conv = tap3*xi+cb; scan -> y = xi*(dt*BC+D)*silu(z).
// ---------------------------------------------------------------------------
__global__ __launch_bounds__(512) void mamba5(
    const unsigned short* __restrict__ hb0, const float* __restrict__ h0,
    const unsigned short* __restrict__ inwb,
    const unsigned short* __restrict__ xwpb,
    const unsigned short* __restrict__ dtwpb,
    const unsigned short* __restrict__ owb,
    const float* __restrict__ conv_w, const float* __restrict__ conv_b,
    const float* __restrict__ dt_b, const float* __restrict__ Dp,
    float* __restrict__ hout) {
  __shared__ __align__(16) unsigned short XiL[32 * 512];  // 32KB xi -> y
  __shared__ __align__(16) unsigned short SzL[32 * 512];  // 32KB silu(z)
  __shared__ __align__(16) unsigned short R1[4][8192];    // 64KB weight ring
  __shared__ __align__(16) unsigned short HLr[8192];      // 16KB h bf16 / dt ring
  __shared__ __align__(16) float Dxl[32 * 64];            // 8KB xdbl
  __shared__ float BCl[32];

  const int t = threadIdx.x, lane = t & 63, w = t >> 6;
  const int lr = lane & 15, lg = lane >> 4;
  const int bm = blockIdx.x * 32;
  const int fm = w & 1, fn = w >> 1;   // wave frag coords (2 x 4)
  const int arow = fm * 16 + lr;       // A-frag LDS row
  const int br = fn * 16 + lr;         // B-frag tile-local row
  const int m0 = fm * 16 + lg * 4;     // C/D frag row base

  // ---- init: stage h bf16 into HLr; load fp32 residual into regs ----
#pragma unroll
  for (int j = 0; j < 2; ++j) {
    const int i = w * 2 + j;  // 16 gl16, 2 rows (512B) each
    const int row = 2 * i + (lane >> 5);
    const int c = (lane & 31) ^ (row & 7);
    gl16(hb0 + (long)(bm + row) * 256 + c * 8, &HLr[i * 512]);
  }
  float hres[4][4];
#pragma unroll
  for (int ng = 0; ng < 4; ++ng)
#pragma unroll
    for (int r = 0; r < 4; ++r)
      hres[ng][r] = h0[(long)(bm + m0 + r) * 256 + ng * 64 + fn * 16 + lr];
  waitv<0>();
  __builtin_amdgcn_s_barrier();

  for (int blk = 0; blk < 5; ++blk) {
    const unsigned short* inw = inwb + (long)blk * 1024 * 256;
    const unsigned short* xwp = xwpb + (long)blk * 64 * 512;
    const unsigned short* dtwp = dtwpb + (long)blk * 512 * 32;
    const unsigned short* ow = owb + (long)blk * 256 * 512;
    const float* cw = conv_w + blk * 512 * 4;
    const float* cbv = conv_b + blk * 512;
    const float* dtbv = dt_b + blk * 512;
    const float* Dv = Dp + blk * 512;

    // ================= P1: xz = h @ in_w^T =================
    auto STAGE1 = [&](int tt, int slot) {
      const int nt = tt >> 1, kh = tt & 1;
#pragma unroll
      for (int j = 0; j < 2; ++j) {
        const int u = w * 2 + j;  // 16 gl16, 4 rows (256B) each
        const int row = 4 * u + (lane >> 4);
        const int c = (lane & 15) ^ (row & 7);
        gl16(inw + (long)(nt * 64 + row) * 256 + kh * 128 + c * 8,
             &R1[slot][u * 512]);
      }
    };
    f32x4 acc1 = {0.f, 0.f, 0.f, 0.f};
    STAGE1(0, 0);
    STAGE1(1, 1);
    for (int tt = 0; tt < 32; ++tt) {
      if (tt + 2 < 32) {
        STAGE1(tt + 2, (tt + 2) & 3);
        waitv<4>();
      } else if (tt + 1 < 32) {
        waitv<2>();
      } else {
        waitv<0>();
      }
      __builtin_amdgcn_s_barrier();
      const int nt = tt >> 1, kh = tt & 1;
      if (kh == 0) acc1 = (f32x4){0.f, 0.f, 0.f, 0.f};
      const unsigned short* Bs = R1[tt & 3];
#pragma unroll
      for (int kc = 0; kc < 4; ++kc) {
        bf16x8 af = *(const bf16x8*)
            &HLr[arow * 256 + ((((kh * 4 + kc) * 4 + lg) ^ (arow & 7)) * 8)];
        bf16x8 bg = *(const bf16x8*)
            &Bs[br * 128 + (((kc * 4 + lg) ^ (br & 7)) * 8)];
        acc1 = __builtin_amdgcn_mfma_f32_16x16x32_bf16(af, bg, acc1, 0, 0, 0);
      }
      if (kh == 1) {
        const int c = nt * 64 + fn * 16 + lr;
        if (c < 512) {
          const float c3 = cw[c * 4 + 3], c0 = cbv[c];
#pragma unroll
          for (int r = 0; r < 4; ++r) {
            const int row = m0 + r;
            XiL[row * 512 + (((c >> 3) ^ (row & 7)) * 8) + (c & 7)] =
                f2b(siluf(acc1[r] * c3 + c0));
          }
        } else {
#pragma unroll
          for (int r = 0; r < 4; ++r) {
            const int row = m0 + r;
            SzL[row * 512 + (c - 512)] = f2b(siluf(acc1[r]));
          }
        }
      }
      __builtin_amdgcn_sched_barrier(0);
    }
    lgkm_bar();  // Xi/Sz writes visible

    // ================= P2: xdbl = xi @ xwp^T =================
#pragma unroll
    for (int j = 0; j < 8; ++j) {
      const int i = w * 8 + j;  // 64 gl16, 1 row (1KB) each
      const int c = lane ^ (i & 7);
      gl16(xwp + (long)i * 512 + c * 8, &R1[0][0] + i * 512);
    }
    waitv<0>();
    __builtin_amdgcn_s_barrier();
    {
      f32x4 a2 = {0.f, 0.f, 0.f, 0.f};
      const unsigned short* Bs = &R1[0][0];
#pragma unroll
      for (int kc = 0; kc < 16; ++kc) {
        bf16x8 af = *(const bf16x8*)
            &XiL[arow * 512 + (((kc * 4 + lg) ^ (arow & 7)) * 8)];
        bf16x8 bg = *(const bf16x8*)
            &Bs[br * 512 + (((kc * 4 + lg) ^ (br & 7)) * 8)];
        a2 = __builtin_amdgcn_mfma_f32_16x16x32_bf16(af, bg, a2, 0, 0, 0);
      }
#pragma unroll
      for (int r = 0; r < 4; ++r) Dxl[(m0 + r) * 64 + fn * 16 + lr] = a2[r];
    }
    lgkm_bar();  // Dxl visible

    // BC per row + dt A-frag (k 16..31 multiply vs zero-padded W: don't care)
    if (t < 32) {
      float bc = 0.f;
      const float* dx = &Dxl[t * 64];
#pragma unroll
      for (int s2 = 0; s2 < 16; ++s2) bc += dx[16 + s2] * dx[32 + s2];
      BCl[t] = bc;
    }
    bf16x8 afdt;
    {
      const float* dx = &Dxl[arow * 64 + lg * 8];
#pragma unroll
      for (int e = 0; e < 8; ++e) afdt[e] = (short)f2b(dx[e]);
    }
    lgkm_bar();  // BCl visible

    // ========== P4: dt = softplus(xdbl[:,:16]@dtwp^T + dtb); y ==========
    auto STAGE4 = [&](int tt, int slot) {
      if (w < 4) {
        const int row = w * 16 + (lane >> 2);  // 4 gl16, 16 rows (64B) each
        const int c = (lane & 3) ^ (row & 3);
        gl16(dtwp + (long)(tt * 64 + row) * 32 + c * 8,
             &HLr[slot * 2048 + w * 512]);
      }
    };
    STAGE4(0, 0);
    waitv<0>();
    __builtin_amdgcn_s_barrier();
    for (int tt = 0; tt < 8; ++tt) {
      if (tt + 1 < 8) STAGE4(tt + 1, (tt + 1) & 1);  // after barrier: slot free
      const unsigned short* Bs = &HLr[(tt & 1) * 2048];
      bf16x8 bg = *(const bf16x8*)&Bs[br * 32 + ((lg ^ (br & 3)) * 8)];
      f32x4 da = __builtin_amdgcn_mfma_f32_16x16x32_bf16(
          afdt, bg, (f32x4){0.f, 0.f, 0.f, 0.f}, 0, 0, 0);
      const int d = tt * 64 + fn * 16 + lr;
      const float dbv = dtbv[d], dvv = Dv[d];
#pragma unroll
      for (int r = 0; r < 4; ++r) {
        const int row = m0 + r;
        const float a = da[r] + dbv;
        const float dtv = (a > 20.f) ? a : log1pf(expf(a));
        const int xoff = row * 512 + (((d >> 3) ^ (row & 7)) * 8) + (d & 7);
        const float y = b2f(XiL[xoff]) * (dtv * BCl[row] + dvv) *
                        b2f(SzL[row * 512 + d]);
        XiL[xoff] = f2b(y);  // y overwrites xi in place (same slot)
      }
      waitv<0>();
      __builtin_amdgcn_s_barrier();
      __builtin_amdgcn_sched_barrier(0);
    }
    lgkm_bar();  // y writes visible

    // ================= P5: h += y @ ow^T =================
    auto STAGE5 = [&](int tt, int slot) {
      const int ng = tt >> 1, kh = tt & 1;
#pragma unroll
      for (int j = 0; j < 4; ++j) {
        const int u = w * 4 + j;  // 32 gl16, 2 rows (512B) each
        const int row = 2 * u + (lane >> 5);
        const int c = (lane & 31) ^ (row & 7);
        gl16(ow + (long)(ng * 64 + row) * 512 + kh * 256 + c * 8,
             &R1[slot * 2][0] + u * 512);
      }
    };
    f32x4 acc5 = {0.f, 0.f, 0.f, 0.f};
    STAGE5(0, 0);
    waitv<0>();
    __builtin_amdgcn_s_barrier();
    for (int tt = 0; tt < 8; ++tt) {
      if (tt + 1 < 8) STAGE5(tt + 1, (tt + 1) & 1);  // after barrier: slot free
      const int ng = tt >> 1, kh = tt & 1;
      if (kh == 0) acc5 = (f32x4){0.f, 0.f, 0.f, 0.f};
      const unsigned short* Bs = &R1[(tt & 1) * 2][0];
#pragma unroll
      for (int kc = 0; kc < 8; ++kc) {
        bf16x8 af = *(const bf16x8*)
            &XiL[arow * 512 + ((((kh * 8 + kc) * 4 + lg) ^ (arow & 7)) * 8)];
        bf16x8 bg = *(const bf16x8*)
            &Bs[br * 256 + (((kc * 4 + lg) ^ (br & 7)) * 8)];
        acc5 = __builtin_amdgcn_mfma_f32_16x16x32_bf16(af, bg, acc5, 0, 0, 0);
      }
      if (kh == 1) {
        const int col = ng * 64 + fn * 16 + lr;
#pragma unroll
        for (int r = 0; r < 4; ++r) {
          const int row = m0 + r;
          const float v = acc5[r] + hres[ng][r];
          hres[ng][r] = v;
          HLr[row * 256 + (((col >> 3) ^ (row & 7)) * 8) + (col & 7)] = f2b(v);
        }
      }
      waitv<0>();
      __builtin_amdgcn_s_barrier();
      __builtin_amdgcn_sched_barrier(0);
    }
    lgkm_bar();  // new HL visible for next block's P1
  }

  // ---- final h fp32 write for LN+cls ----
#pragma unroll
  for (int ng = 0; ng < 4; ++ng)
#pragma unroll
    for (int r = 0; r < 4; ++r)
      hout[(long)(bm + m0 + r) * 256 + ng * 64 + fn * 16 + lr] = hres[ng][r];
}

// x fp32 -> bf16 streaming cast (8192*2048 elems)
__global__ __launch_bounds__(256) void castx(const float* __restrict__ s,
                                             unsigned short* __restrict__ d) {
  const int n4 = (8192 * 2048) / 4;
  for (int i = blockIdx.x * 256 + threadIdx.x; i < n4; i += gridDim.x * 256) {
    float4v v = ((const float4v*)s)[i];
    s16x4 o;
    o[0] = (short)f2b(v[0]); o[1] = (short)f2b(v[1]);
    o[2] = (short)f2b(v[2]); o[3] = (short)f2b(v[3]);
    ((s16x4*)d)[i] = o;
  }
}

// weight precast: W_pre/in_w/out_w -> bf16; x_proj -> padded [64x512];
// dt_w -> padded bf16 [512 x 32] (k>=16 zero)
__global__ __launch_bounds__(256) void precast(
    const float* __restrict__ wpre, const float* __restrict__ inw,
    const float* __restrict__ ow, const float* __restrict__ xw,
    const float* __restrict__ dtw,
    unsigned short* __restrict__ wpreb, unsigned short* __restrict__ inwb,
    unsigned short* __restrict__ owb, unsigned short* __restrict__ xwpb,
    unsigned short* __restrict__ dtwpb) {
  const int S0 = 524288;         // 256*2048
  const int S1 = S0 + 1310720;   // + 5*1024*256
  const int S2 = S1 + 655360;    // + 5*256*512
  const int S3 = S2 + 163840;    // + 5*64*512
  const int S4 = S3 + 81920;     // + 5*512*32
  int i4 = (blockIdx.x * 256 + threadIdx.x) * 4;
  if (i4 >= S4) return;
  float4v v = {0.f, 0.f, 0.f, 0.f};
  unsigned short* dst;
  if (i4 < S0) {
    v = *(const float4v*)(wpre + i4);
    dst = wpreb + i4;
  } else if (i4 < S1) {
    int o = i4 - S0;
    v = *(const float4v*)(inw + o);
    dst = inwb + o;
  } else if (i4 < S2) {
    int o = i4 - S1;
    v = *(const float4v*)(ow + o);
    dst = owb + o;
  } else if (i4 < S3) {
    int o = i4 - S2;
    dst = xwpb + o;
    int k = o & 511, j = (o >> 9) & 63, b = o >> 15;
    if (j < 48) v = *(const float4v*)(xw + ((long)(b * 48 + j)) * 512 + k);
  } else {
    int o = i4 - S3;
    dst = dtwpb + o;
    int k = o & 31, dd = o >> 5;  // dd = b*512 + d
    if (k < 16) v = *(const float4v*)(dtw + (long)dd * 16 + k);
  }
  s16x4 sv;
  sv[0] = (short)f2b(v[0]); sv[1] = (short)f2b(v[1]);
  sv[2] = (short)f2b(v[2]); sv[3] = (short)f2b(v[3]);
  *(s16x4*)dst = sv;
}

// LayerNorm(256) + classifier (8 outputs). One wave per row.
__global__ __launch_bounds__(256) void final_ln_cls(
    const float* __restrict__ h, const float* __restrict__ g,
    const float* __restrict__ be, const float* __restrict__ Wc,
    const float* __restrict__ bc, float* __restrict__ out) {
  const int wave = threadIdx.x >> 6, lane = threadIdx.x & 63;
  const int row = blockIdx.x * 4 + wave;
  const float4v* hr = (const float4v*)(h + (long)row * 256);
  float4v v = hr[lane];
  float s = v[0] + v[1] + v[2] + v[3];
#pragma unroll
  for (int o = 32; o; o >>= 1) s += __shfl_xor(s, o);
  const float mu = s * (1.f / 256.f);
  float d0 = v[0] - mu, d1 = v[1] - mu, d2 = v[2] - mu, d3 = v[3] - mu;
  float qq = d0 * d0 + d1 * d1 + d2 * d2 + d3 * d3;
#pragma unroll
  for (int o = 32; o; o >>= 1) qq += __shfl_xor(qq, o);
  const float rs = rsqrtf(qq * (1.f / 256.f) + 1e-5f);
  const float4v gv = ((const float4v*)g)[lane];
  const float4v bv = ((const float4v*)be)[lane];
  float hn[4];
  hn[0] = d0 * rs * gv[0] + bv[0];
  hn[1] = d1 * rs * gv[1] + bv[1];
  hn[2] = d2 * rs * gv[2] + bv[2];
  hn[3] = d3 * rs * gv[3] + bv[3];
  float lg[8];
#pragma unroll
  for (int o = 0; o < 8; ++o) {
    const float4v wv = ((const float4v*)(Wc + o * 256))[lane];
    float p = hn[0] * wv[0] + hn[1] * wv[1] + hn[2] * wv[2] + hn[3] * wv[3];
#pragma unroll
    for (int x = 32; x; x >>= 1) p += __shfl_xor(p, x);
    lg[o] = p;
  }
  if (lane == 0) {
#pragma unroll
    for (int o = 0; o < 8; ++o) out[(long)row * 8 + o] = lg[o] + bc[o];
  }
}

extern "C" void kernel_launch(void* const* d_in, const int* in_sizes, int n_in,
                              void* d_out, int out_size, void* d_ws,
                              size_t ws_size, hipStream_t stream) {
  const float* x      = (const float*)d_in[0];
  const float* W_pre  = (const float*)d_in[1];
  const float* b_pre  = (const float*)d_in[2];
  const float* in_w   = (const float*)d_in[3];
  const float* conv_w = (const float*)d_in[4];
  const float* conv_b = (const float*)d_in[5];
  const float* x_w    = (const float*)d_in[6];
  const float* dt_w   = (const float*)d_in[7];
  const float* dt_b   = (const float*)d_in[8];
  // d_in[9] = A_log: dead (scan starts from h0=0 and L=1)
  const float* Dp     = (const float*)d_in[10];
  const float* out_w  = (const float*)d_in[11];
  const float* ln_g   = (const float*)d_in[12];
  const float* ln_b   = (const float*)d_in[13];
  const float* W_cls  = (const float*)d_in[14];
  const float* b_cls  = (const float*)d_in[15];
  float* out = (float*)d_out;

  char* w = (char*)d_ws;
  unsigned short* wpreb = (unsigned short*)w; w += 256 * 2048 * 2;
  unsigned short* inwb  = (unsigned short*)w; w += 5 * 1024 * 256 * 2;
  unsigned short* xwpb  = (unsigned short*)w; w += 5 * 64 * 512 * 2;
  unsigned short* owb   = (unsigned short*)w; w += 5 * 256 * 512 * 2;
  unsigned short* dtwpb = (unsigned short*)w; w += 5 * 512 * 32 * 2;
  float*          h     = (float*)w;          w += 8192 * 256 * 4;
  unsigned short* hb    = (unsigned short*)w; w += 8192 * 256 * 2;
  unsigned short* xb    = (unsigned short*)w; w += 8192 * 2048 * 2;

  precast<<<2672, 256, 0, stream>>>(W_pre, in_w, out_w, x_w, dt_w,
                                    wpreb, inwb, owb, xwpb, dtwpb);
  castx<<<2048, 256, 0, stream>>>(x, xb);

  // h = x @ W_pre^T + b_pre  (fp32 of + bf16 ob)
  gemm_pl<0, 128, 64><<<256, 256, 0, stream>>>(
      xb, wpreb, 256, 2048, 4, b_pre, h, hb);

  // all 5 Mamba blocks, one persistent kernel, h resident
  mamba5<<<256, 512, 0, stream>>>(hb, h, inwb, xwpb, dtwpb, owb,
                                  conv_w, conv_b, dt_b, Dp, h);

  final_ln_cls<<<2048, 256, 0, stream>>>(h, ln_g, ln_b, W_cls, b_cls, out);
}

// Round 8
// 241.584 us; speedup vs baseline: 1.7818x; 1.3441x over previous
//
#include <hip/hip_runtime.h>
#include <hip/hip_bf16.h>

typedef __attribute__((ext_vector_type(8))) short bf16x8;
typedef __attribute__((ext_vector_type(4))) short s16x4;
typedef __attribute__((ext_vector_type(4))) float f32x4;
typedef __attribute__((ext_vector_type(4))) float float4v;

static __device__ __forceinline__ unsigned short f2b(float f) {
  unsigned int u = __builtin_bit_cast(unsigned int, f);
  u += 0x7fffu + ((u >> 16) & 1u);
  return (unsigned short)(u >> 16);
}
static __device__ __forceinline__ float b2f(unsigned short s) {
  unsigned int u = ((unsigned int)s) << 16;
  return __builtin_bit_cast(float, u);
}
// fast silu/softplus on TRANS pipe (v_exp/v_log/v_rcp); bf16-accurate
static __device__ __forceinline__ float fsilu(float x) {
  float e = __builtin_amdgcn_exp2f(-1.44269504f * x);
  return x * __builtin_amdgcn_rcpf(1.f + e);
}
static __device__ __forceinline__ float fsoftplus(float a) {
  if (a > 20.f) return a;
  float t = __builtin_amdgcn_exp2f(1.44269504f * a);
  return 0.69314718f * __builtin_amdgcn_logf(1.f + t);
}
static __device__ __forceinline__ float siluf(float x) {  // for gemm_pl epilogue
  return fsilu(x);
}
// async global->LDS, 16B/lane; LDS dest wave-uniform base + lane*16,
// global source per-lane (enables source-side swizzling, rule #21)
static __device__ __forceinline__ void gl16(const void* g, void* l) {
  __builtin_amdgcn_global_load_lds(
      (const __attribute__((address_space(1))) unsigned int*)g,
      (__attribute__((address_space(3))) unsigned int*)l, 16, 0, 0);
}
template <int N>
static __device__ __forceinline__ void waitv() {
  if constexpr (N == 0) asm volatile("s_waitcnt vmcnt(0)" ::: "memory");
  else if constexpr (N == 2) asm volatile("s_waitcnt vmcnt(2)" ::: "memory");
  else if constexpr (N == 3) asm volatile("s_waitcnt vmcnt(3)" ::: "memory");
  else if constexpr (N == 4) asm volatile("s_waitcnt vmcnt(4)" ::: "memory");
  else if constexpr (N == 6) asm volatile("s_waitcnt vmcnt(6)" ::: "memory");
  else if constexpr (N == 8) asm volatile("s_waitcnt vmcnt(8)" ::: "memory");
}
static __device__ __forceinline__ void lgkm_bar() {
  asm volatile("s_waitcnt lgkmcnt(0)" ::: "memory");
  __builtin_amdgcn_s_barrier();
}

// ---------------------------------------------------------------------------
// pre-GEMM: C = A @ W^T, bf16 MFMA, fp32 accum. TM x TN, BK=32, 4 waves,
// depth-4 ring, counted vmcnt, chunk-XOR swizzle, bijective XCD swizzle.
// Epilogue: v += bias; fp32 of[] + bf16 ob[].
// ---------------------------------------------------------------------------
template <int MODE, int TM, int TN>
__global__ __launch_bounds__(256) void gemm_pl(
    const unsigned short* __restrict__ A, const unsigned short* __restrict__ W,
    int N, int K, int GY,
    const float* __restrict__ p0, float* __restrict__ of,
    unsigned short* __restrict__ ob) {
  constexpr int FM = TM / 32, FN = TN / 32;
  constexpr int IA = TM / 64, IW = TN / 64;
  constexpr int LPT = IA + IW;
  __shared__ __align__(16) unsigned short As[4][TM * 32];
  __shared__ __align__(16) unsigned short Ws[4][TN * 32];

  const int t = threadIdx.x, lane = t & 63, wave = t >> 6;
  const int lr = lane & 15;
  const int q = gridDim.x >> 3;
  const int s = (blockIdx.x & 7) * q + (blockIdx.x >> 3);
  const int bm = (s / GY) * TM, bn = (s % GY) * TN;
  const int wr = (wave >> 1) * (TM / 2), wc = (wave & 1) * (TN / 2);

  f32x4 acc[FM][FN];
#pragma unroll
  for (int i = 0; i < FM; ++i)
#pragma unroll
    for (int j = 0; j < FN; ++j) acc[i][j] = (f32x4){0.f, 0.f, 0.f, 0.f};

  const unsigned short* agB =
      A + (long)(bm + wave * (TM / 4) + (lane >> 2)) * K +
      ((lane & 3) ^ ((lane >> 3) & 3)) * 8;
  const unsigned short* wgB =
      W + (long)(bn + wave * (TN / 4) + (lane >> 2)) * K +
      ((lane & 3) ^ ((lane >> 3) & 3)) * 8;

  auto STAGE = [&](int k0, int b) {
#pragma unroll
    for (int j = 0; j < IA; ++j)
      gl16(agB + k0 + (long)j * 16 * K, &As[b][(wave * (TM / 4) + j * 16) * 32]);
#pragma unroll
    for (int j = 0; j < IW; ++j)
      gl16(wgB + k0 + (long)j * 16 * K, &Ws[b][(wave * (TN / 4) + j * 16) * 32]);
  };

  auto COMPUTE = [&](int b) {
    bf16x8 af[FM], bg[FN];
    const int sw = ((lane >> 4) ^ ((lane >> 1) & 3)) * 8;
#pragma unroll
    for (int m = 0; m < FM; ++m)
      af[m] = *(const bf16x8*)&As[b][(wr + m * 16 + lr) * 32 + sw];
#pragma unroll
    for (int n = 0; n < FN; ++n)
      bg[n] = *(const bf16x8*)&Ws[b][(wc + n * 16 + lr) * 32 + sw];
    __builtin_amdgcn_s_setprio(1);
#pragma unroll
    for (int m = 0; m < FM; ++m)
#pragma unroll
      for (int n = 0; n < FN; ++n)
        acc[m][n] = __builtin_amdgcn_mfma_f32_16x16x32_bf16(af[m], bg[n],
                                                            acc[m][n], 0, 0, 0);
    __builtin_amdgcn_s_setprio(0);
  };

  const int NT = K >> 5;
  STAGE(0, 0);
  STAGE(32, 1);
  for (int tt = 0; tt < NT; ++tt) {
    if (tt + 2 < NT) {
      STAGE((tt + 2) << 5, (tt + 2) & 3);
      waitv<2 * LPT>();
    } else if (tt + 1 < NT) {
      waitv<LPT>();
    } else {
      waitv<0>();
    }
    __builtin_amdgcn_s_barrier();
    COMPUTE(tt & 3);
    __builtin_amdgcn_sched_barrier(0);
  }

  const int m0 = bm + wr + (lane >> 4) * 4;
  const int n0 = bn + wc + lr;
#pragma unroll
  for (int mi = 0; mi < FM; ++mi)
#pragma unroll
    for (int ni = 0; ni < FN; ++ni) {
      const int n = n0 + ni * 16;
#pragma unroll
      for (int r = 0; r < 4; ++r) {
        const int m = m0 + mi * 16 + r;
        float v = acc[mi][ni][r] + p0[n];
        of[(long)m * N + n] = v;
        ob[(long)m * N + n] = f2b(v);
      }
    }
}

// ---------------------------------------------------------------------------
// mamba5: all 5 Mamba blocks fused. Grid 256 x 512thr, 32 rows/block,
// h resident (fp32 regs + bf16 LDS). Per block:
//   P1 in_proj: 32 tiles [64Nx128K] ring4 depth-2 counted vmcnt
//   P2 xdbl = xi @ xwp^T (64KB staged whole)
//   P4 dt-GEMM: dtwp 32KB staged once, 8 barrier-free MFMA iters + y epilogue
//   P5 out_proj: 16 tiles [64Nx128K] ring4 depth-2 counted vmcnt + residual
// All LDS frag reads chunk-XOR swizzled (pos p holds logical chunk p^(row&7)).
// L=1 collapse: conv = tap3*xi+cb; scan -> y = xi*(dt*BC+D)*silu(z).
// ---------------------------------------------------------------------------
__global__ __launch_bounds__(512) void mamba5(
    const unsigned short* __restrict__ hb0, const float* __restrict__ h0,
    const unsigned short* __restrict__ inwb,
    const unsigned short* __restrict__ xwpb,
    const unsigned short* __restrict__ dtwpb,
    const unsigned short* __restrict__ owb,
    const float* __restrict__ conv_w, const float* __restrict__ conv_b,
    const float* __restrict__ dt_b, const float* __restrict__ Dp,
    float* __restrict__ hout) {
  __shared__ __align__(16) unsigned short XiL[32 * 512];  // 32KB xi -> y
  __shared__ __align__(16) unsigned short SzL[32 * 512];  // 32KB silu(z)
  __shared__ __align__(16) unsigned short R1[4][8192];    // 64KB weight ring
  __shared__ __align__(16) unsigned short HLr[8192];      // 16KB h bf16
  __shared__ __align__(16) float Dxl[32 * 64];            // 8KB xdbl
  __shared__ float BCl[32];

  const int t = threadIdx.x, lane = t & 63, w = t >> 6;
  const int lr = lane & 15, lg = lane >> 4;
  const int bm = blockIdx.x * 32;
  const int fm = w & 1, fn = w >> 1;   // wave frag coords (2 x 4)
  const int arow = fm * 16 + lr;       // A-frag LDS row
  const int br = fn * 16 + lr;         // B-frag tile-local row
  const int m0 = fm * 16 + lg * 4;     // C/D frag row base

  // ---- init: stage h bf16 into HLr; load fp32 residual into regs ----
#pragma unroll
  for (int j = 0; j < 2; ++j) {
    const int i = w * 2 + j;  // 16 gl16, 2 rows (512B) each
    const int row = 2 * i + (lane >> 5);
    const int c = (lane & 31) ^ (row & 7);
    gl16(hb0 + (long)(bm + row) * 256 + c * 8, &HLr[i * 512]);
  }
  float hres[4][4];
#pragma unroll
  for (int ng = 0; ng < 4; ++ng)
#pragma unroll
    for (int r = 0; r < 4; ++r)
      hres[ng][r] = h0[(long)(bm + m0 + r) * 256 + ng * 64 + fn * 16 + lr];
  waitv<0>();
  __builtin_amdgcn_s_barrier();

  for (int blk = 0; blk < 5; ++blk) {
    const unsigned short* inw = inwb + (long)blk * 1024 * 256;
    const unsigned short* xwp = xwpb + (long)blk * 64 * 512;
    const unsigned short* dtwp = dtwpb + (long)blk * 512 * 32;
    const unsigned short* ow = owb + (long)blk * 256 * 512;
    const float* cw = conv_w + blk * 512 * 4;
    const float* cbv = conv_b + blk * 512;
    const float* dtbv = dt_b + blk * 512;
    const float* Dv = Dp + blk * 512;

    // ================= P1: xz = h @ in_w^T =================
    auto STAGE1 = [&](int tt, int slot) {
      const int nt = tt >> 1, kh = tt & 1;
#pragma unroll
      for (int j = 0; j < 2; ++j) {
        const int u = w * 2 + j;  // 16 gl16, 4 rows (256B) each
        const int row = 4 * u + (lane >> 4);
        const int c = (lane & 15) ^ (row & 7);
        gl16(inw + (long)(nt * 64 + row) * 256 + kh * 128 + c * 8,
             &R1[slot][u * 512]);
      }
    };
    f32x4 acc1 = {0.f, 0.f, 0.f, 0.f};
    STAGE1(0, 0);
    STAGE1(1, 1);
    for (int tt = 0; tt < 32; ++tt) {
      if (tt + 2 < 32) {
        STAGE1(tt + 2, (tt + 2) & 3);
        waitv<4>();
      } else if (tt + 1 < 32) {
        waitv<2>();
      } else {
        waitv<0>();
      }
      __builtin_amdgcn_s_barrier();
      const int nt = tt >> 1, kh = tt & 1;
      if (kh == 0) acc1 = (f32x4){0.f, 0.f, 0.f, 0.f};
      const unsigned short* Bs = R1[tt & 3];
#pragma unroll
      for (int kc = 0; kc < 4; ++kc) {
        bf16x8 af = *(const bf16x8*)
            &HLr[arow * 256 + ((((kh * 4 + kc) * 4 + lg) ^ (arow & 7)) * 8)];
        bf16x8 bg = *(const bf16x8*)
            &Bs[br * 128 + (((kc * 4 + lg) ^ (br & 7)) * 8)];
        acc1 = __builtin_amdgcn_mfma_f32_16x16x32_bf16(af, bg, acc1, 0, 0, 0);
      }
      if (kh == 1) {
        const int c = nt * 64 + fn * 16 + lr;
        if (c < 512) {
          const float c3 = cw[c * 4 + 3], c0 = cbv[c];
#pragma unroll
          for (int r = 0; r < 4; ++r) {
            const int row = m0 + r;
            XiL[row * 512 + (((c >> 3) ^ (row & 7)) * 8) + (c & 7)] =
                f2b(fsilu(acc1[r] * c3 + c0));
          }
        } else {
#pragma unroll
          for (int r = 0; r < 4; ++r) {
            const int row = m0 + r;
            SzL[row * 512 + (c - 512)] = f2b(fsilu(acc1[r]));
          }
        }
      }
      __builtin_amdgcn_sched_barrier(0);
    }
    lgkm_bar();  // Xi/Sz writes visible

    // ================= P2: xdbl = xi @ xwp^T =================
#pragma unroll
    for (int j = 0; j < 8; ++j) {
      const int i = w * 8 + j;  // 64 gl16, 1 row (1KB) each
      const int c = lane ^ (i & 7);
      gl16(xwp + (long)i * 512 + c * 8, &R1[0][0] + i * 512);
    }
    waitv<0>();
    __builtin_amdgcn_s_barrier();
    {
      f32x4 a2 = {0.f, 0.f, 0.f, 0.f};
      const unsigned short* Bs = &R1[0][0];
#pragma unroll
      for (int kc = 0; kc < 16; ++kc) {
        bf16x8 af = *(const bf16x8*)
            &XiL[arow * 512 + (((kc * 4 + lg) ^ (arow & 7)) * 8)];
        bf16x8 bg = *(const bf16x8*)
            &Bs[br * 512 + (((kc * 4 + lg) ^ (br & 7)) * 8)];
        a2 = __builtin_amdgcn_mfma_f32_16x16x32_bf16(af, bg, a2, 0, 0, 0);
      }
#pragma unroll
      for (int r = 0; r < 4; ++r) Dxl[(m0 + r) * 64 + fn * 16 + lr] = a2[r];
    }
    lgkm_bar();  // Dxl visible (R1 reads retired)

    // ===== P4 prologue: stage whole dtwp [512x32]=32KB into R1[0..1];
    // overlap with BC + afdt prep =====
#pragma unroll
    for (int j = 0; j < 4; ++j) {
      const int u = w * 4 + j;  // 32 gl16, 16 rows (64B) each
      const int row = u * 16 + (lane >> 2);
      const int c = (lane & 3) ^ (row & 3);
      gl16(dtwp + (long)row * 32 + c * 8, &R1[0][0] + u * 512);
    }
    if (t < 32) {
      float bc = 0.f;
      const float* dx = &Dxl[t * 64];
#pragma unroll
      for (int s2 = 0; s2 < 16; ++s2) bc += dx[16 + s2] * dx[32 + s2];
      BCl[t] = bc;
    }
    bf16x8 afdt;
    {
      // k 16..31 multiply vs zero-padded dtwp rows: contributes 0
      const float* dx = &Dxl[arow * 64 + lg * 8];
#pragma unroll
      for (int e = 0; e < 8; ++e) afdt[e] = (short)f2b(dx[e]);
    }
    waitv<0>();
    lgkm_bar();  // dtwp staged + BCl visible

    // ===== P4: dt = softplus(xdbl[:,:16]@dtwp^T + dtb); y (barrier-free) =====
    for (int tt = 0; tt < 8; ++tt) {
      const int d = tt * 64 + fn * 16 + lr;
      bf16x8 bg = *(const bf16x8*)&R1[0][d * 32 + ((lg ^ (d & 3)) * 8)];
      f32x4 da = __builtin_amdgcn_mfma_f32_16x16x32_bf16(
          afdt, bg, (f32x4){0.f, 0.f, 0.f, 0.f}, 0, 0, 0);
      const float dbv = dtbv[d], dvv = Dv[d];
#pragma unroll
      for (int r = 0; r < 4; ++r) {
        const int row = m0 + r;
        const float dtv = fsoftplus(da[r] + dbv);
        const int xoff = row * 512 + (((d >> 3) ^ (row & 7)) * 8) + (d & 7);
        const float y = b2f(XiL[xoff]) * (dtv * BCl[row] + dvv) *
                        b2f(SzL[row * 512 + d]);
        XiL[xoff] = f2b(y);  // y overwrites xi in place
      }
    }
    lgkm_bar();  // y writes visible (R1 reads retired)

    // ===== P5: h += y @ ow^T  (16 tiles [64Nx128K], ring4 depth-2) =====
    auto STAGE5 = [&](int tt, int slot) {
      const int ng = tt >> 2, kq = tt & 3;
#pragma unroll
      for (int j = 0; j < 2; ++j) {
        const int u = w * 2 + j;  // 16 gl16, 4 rows (256B) each
        const int row = u * 4 + (lane >> 4);
        const int c = (lane & 15) ^ (row & 7);
        gl16(ow + (long)(ng * 64 + row) * 512 + kq * 128 + c * 8,
             &R1[slot][u * 512]);
      }
    };
    f32x4 acc5 = {0.f, 0.f, 0.f, 0.f};
    STAGE5(0, 0);
    STAGE5(1, 1);
    for (int tt = 0; tt < 16; ++tt) {
      if (tt + 2 < 16) {
        STAGE5(tt + 2, (tt + 2) & 3);
        waitv<4>();
      } else if (tt + 1 < 16) {
        waitv<2>();
      } else {
        waitv<0>();
      }
      __builtin_amdgcn_s_barrier();
      const int ng = tt >> 2, kq = tt & 3;
      if (kq == 0) acc5 = (f32x4){0.f, 0.f, 0.f, 0.f};
      const unsigned short* Bs = R1[tt & 3];
#pragma unroll
      for (int kc = 0; kc < 4; ++kc) {
        bf16x8 af = *(const bf16x8*)
            &XiL[arow * 512 + (((kq * 16 + kc * 4 + lg) ^ (arow & 7)) * 8)];
        bf16x8 bg = *(const bf16x8*)
            &Bs[br * 128 + (((kc * 4 + lg) ^ (br & 7)) * 8)];
        acc5 = __builtin_amdgcn_mfma_f32_16x16x32_bf16(af, bg, acc5, 0, 0, 0);
      }
      if (kq == 3) {
        const int col = ng * 64 + fn * 16 + lr;
#pragma unroll
        for (int r = 0; r < 4; ++r) {
          const int row = m0 + r;
          const float v = acc5[r] + hres[ng][r];
          hres[ng][r] = v;
          HLr[row * 256 + (((col >> 3) ^ (row & 7)) * 8) + (col & 7)] = f2b(v);
        }
      }
      __builtin_amdgcn_sched_barrier(0);
    }
    lgkm_bar();  // new HL visible for next block's P1
  }

  // ---- final h fp32 write for LN+cls ----
#pragma unroll
  for (int ng = 0; ng < 4; ++ng)
#pragma unroll
    for (int r = 0; r < 4; ++r)
      hout[(long)(bm + m0 + r) * 256 + ng * 64 + fn * 16 + lr] = hres[ng][r];
}

// x fp32 -> bf16 streaming cast (8192*2048 elems)
__global__ __launch_bounds__(256) void castx(const float* __restrict__ s,
                                             unsigned short* __restrict__ d) {
  const int n4 = (8192 * 2048) / 4;
  for (int i = blockIdx.x * 256 + threadIdx.x; i < n4; i += gridDim.x * 256) {
    float4v v = ((const float4v*)s)[i];
    s16x4 o;
    o[0] = (short)f2b(v[0]); o[1] = (short)f2b(v[1]);
    o[2] = (short)f2b(v[2]); o[3] = (short)f2b(v[3]);
    ((s16x4*)d)[i] = o;
  }
}

// weight precast: W_pre/in_w/out_w -> bf16; x_proj -> padded [64x512];
// dt_w -> padded bf16 [512 x 32] (k>=16 zero)
__global__ __launch_bounds__(256) void precast(
    const float* __restrict__ wpre, const float* __restrict__ inw,
    const float* __restrict__ ow, const float* __restrict__ xw,
    const float* __restrict__ dtw,
    unsigned short* __restrict__ wpreb, unsigned short* __restrict__ inwb,
    unsigned short* __restrict__ owb, unsigned short* __restrict__ xwpb,
    unsigned short* __restrict__ dtwpb) {
  const int S0 = 524288;         // 256*2048
  const int S1 = S0 + 1310720;   // + 5*1024*256
  const int S2 = S1 + 655360;    // + 5*256*512
  const int S3 = S2 + 163840;    // + 5*64*512
  const int S4 = S3 + 81920;     // + 5*512*32
  int i4 = (blockIdx.x * 256 + threadIdx.x) * 4;
  if (i4 >= S4) return;
  float4v v = {0.f, 0.f, 0.f, 0.f};
  unsigned short* dst;
  if (i4 < S0) {
    v = *(const float4v*)(wpre + i4);
    dst = wpreb + i4;
  } else if (i4 < S1) {
    int o = i4 - S0;
    v = *(const float4v*)(inw + o);
    dst = inwb + o;
  } else if (i4 < S2) {
    int o = i4 - S1;
    v = *(const float4v*)(ow + o);
    dst = owb + o;
  } else if (i4 < S3) {
    int o = i4 - S2;
    dst = xwpb + o;
    int k = o & 511, j = (o >> 9) & 63, b = o >> 15;
    if (j < 48) v = *(const float4v*)(xw + ((long)(b * 48 + j)) * 512 + k);
  } else {
    int o = i4 - S3;
    dst = dtwpb + o;
    int k = o & 31, dd = o >> 5;  // dd = b*512 + d
    if (k < 16) v = *(const float4v*)(dtw + (long)dd * 16 + k);
  }
  s16x4 sv;
  sv[0] = (short)f2b(v[0]); sv[1] = (short)f2b(v[1]);
  sv[2] = (short)f2b(v[2]); sv[3] = (short)f2b(v[3]);
  *(s16x4*)dst = sv;
}

// LayerNorm(256) + classifier (8 outputs). One wave per row.
__global__ __launch_bounds__(256) void final_ln_cls(
    const float* __restrict__ h, const float* __restrict__ g,
    const float* __restrict__ be, const float* __restrict__ Wc,
    const float* __restrict__ bc, float* __restrict__ out) {
  const int wave = threadIdx.x >> 6, lane = threadIdx.x & 63;
  const int row = blockIdx.x * 4 + wave;
  const float4v* hr = (const float4v*)(h + (long)row * 256);
  float4v v = hr[lane];
  float s = v[0] + v[1] + v[2] + v[3];
#pragma unroll
  for (int o = 32; o; o >>= 1) s += __shfl_xor(s, o);
  const float mu = s * (1.f / 256.f);
  float d0 = v[0] - mu, d1 = v[1] - mu, d2 = v[2] - mu, d3 = v[3] - mu;
  float qq = d0 * d0 + d1 * d1 + d2 * d2 + d3 * d3;
#pragma unroll
  for (int o = 32; o; o >>= 1) qq += __shfl_xor(qq, o);
  const float rs = rsqrtf(qq * (1.f / 256.f) + 1e-5f);
  const float4v gv = ((const float4v*)g)[lane];
  const float4v bv = ((const float4v*)be)[lane];
  float hn[4];
  hn[0] = d0 * rs * gv[0] + bv[0];
  hn[1] = d1 * rs * gv[1] + bv[1];
  hn[2] = d2 * rs * gv[2] + bv[2];
  hn[3] = d3 * rs * gv[3] + bv[3];
  float lg[8];
#pragma unroll
  for (int o = 0; o < 8; ++o) {
    const float4v wv = ((const float4v*)(Wc + o * 256))[lane];
    float p = hn[0] * wv[0] + hn[1] * wv[1] + hn[2] * wv[2] + hn[3] * wv[3];
#pragma unroll
    for (int x = 32; x; x >>= 1) p += __shfl_xor(p, x);
    lg[o] = p;
  }
  if (lane == 0) {
#pragma unroll
    for (int o = 0; o < 8; ++o) out[(long)row * 8 + o] = lg[o] + bc[o];
  }
}

extern "C" void kernel_launch(void* const* d_in, const int* in_sizes, int n_in,
                              void* d_out, int out_size, void* d_ws,
                              size_t ws_size, hipStream_t stream) {
  const float* x      = (const float*)d_in[0];
  const float* W_pre  = (const float*)d_in[1];
  const float* b_pre  = (const float*)d_in[2];
  const float* in_w   = (const float*)d_in[3];
  const float* conv_w = (const float*)d_in[4];
  const float* conv_b = (const float*)d_in[5];
  const float* x_w    = (const float*)d_in[6];
  const float* dt_w   = (const float*)d_in[7];
  const float* dt_b   = (const float*)d_in[8];
  // d_in[9] = A_log: dead (scan starts from h0=0 and L=1)
  const float* Dp     = (const float*)d_in[10];
  const float* out_w  = (const float*)d_in[11];
  const float* ln_g   = (const float*)d_in[12];
  const float* ln_b   = (const float*)d_in[13];
  const float* W_cls  = (const float*)d_in[14];
  const float* b_cls  = (const float*)d_in[15];
  float* out = (float*)d_out;

  char* w = (char*)d_ws;
  unsigned short* wpreb = (unsigned short*)w; w += 256 * 2048 * 2;
  unsigned short* inwb  = (unsigned short*)w; w += 5 * 1024 * 256 * 2;
  unsigned short* xwpb  = (unsigned short*)w; w += 5 * 64 * 512 * 2;
  unsigned short* owb   = (unsigned short*)w; w += 5 * 256 * 512 * 2;
  unsigned short* dtwpb = (unsigned short*)w; w += 5 * 512 * 32 * 2;
  float*          h     = (float*)w;          w += 8192 * 256 * 4;
  unsigned short* hb    = (unsigned short*)w; w += 8192 * 256 * 2;
  unsigned short* xb    = (unsigned short*)w; w += 8192 * 2048 * 2;

  precast<<<2672, 256, 0, stream>>>(W_pre, in_w, out_w, x_w, dt_w,
                                    wpreb, inwb, owb, xwpb, dtwpb);
  castx<<<2048, 256, 0, stream>>>(x, xb);

  // h = x @ W_pre^T + b_pre  (fp32 of + bf16 ob)
  gemm_pl<0, 128, 64><<<256, 256, 0, stream>>>(
      xb, wpreb, 256, 2048, 4, b_pre, h, hb);

  // all 5 Mamba blocks, one persistent kernel, h resident
  mamba5<<<256, 512, 0, stream>>>(hb, h, inwb, xwpb, dtwpb, owb,
                                  conv_w, conv_b, dt_b, Dp, h);

  final_ln_cls<<<2048, 256, 0, stream>>>(h, ln_g, ln_b, W_cls, b_cls, out);
}

// Round 10
// 220.694 us; speedup vs baseline: 1.9504x; 1.0947x over previous
//
#include <hip/hip_runtime.h>
#include <hip/hip_bf16.h>

typedef __attribute__((ext_vector_type(8))) short bf16x8;
typedef __attribute__((ext_vector_type(4))) short s16x4;
typedef __attribute__((ext_vector_type(4))) float f32x4;
typedef __attribute__((ext_vector_type(4))) float float4v;

static __device__ __forceinline__ unsigned short f2b(float f) {
  unsigned int u = __builtin_bit_cast(unsigned int, f);
  u += 0x7fffu + ((u >> 16) & 1u);
  return (unsigned short)(u >> 16);
}
static __device__ __forceinline__ float b2f(unsigned short s) {
  unsigned int u = ((unsigned int)s) << 16;
  return __builtin_bit_cast(float, u);
}
// fast silu/softplus on TRANS pipe; bf16-accurate
static __device__ __forceinline__ float fsilu(float x) {
  float e = __builtin_amdgcn_exp2f(-1.44269504f * x);
  return x * __builtin_amdgcn_rcpf(1.f + e);
}
static __device__ __forceinline__ float fsoftplus(float a) {
  if (a > 20.f) return a;
  float t = __builtin_amdgcn_exp2f(1.44269504f * a);
  return 0.69314718f * __builtin_amdgcn_logf(1.f + t);  // ln2*log2 = ln
}
// async global->LDS, 16B/lane; dest wave-uniform base + lane*16,
// source per-lane (enables source-side swizzling, rule #21)
static __device__ __forceinline__ void gl16(const void* g, void* l) {
  __builtin_amdgcn_global_load_lds(
      (const __attribute__((address_space(1))) unsigned int*)g,
      (__attribute__((address_space(3))) unsigned int*)l, 16, 0, 0);
}
template <int N>
static __device__ __forceinline__ void waitv() {
  if constexpr (N == 0) asm volatile("s_waitcnt vmcnt(0)" ::: "memory");
  else if constexpr (N == 2) asm volatile("s_waitcnt vmcnt(2)" ::: "memory");
  else if constexpr (N == 4) asm volatile("s_waitcnt vmcnt(4)" ::: "memory");
  else if constexpr (N == 6) asm volatile("s_waitcnt vmcnt(6)" ::: "memory");
  else if constexpr (N == 8) asm volatile("s_waitcnt vmcnt(8)" ::: "memory");
}
static __device__ __forceinline__ void lgkm_bar() {
  asm volatile("s_waitcnt lgkmcnt(0)" ::: "memory");
  __builtin_amdgcn_s_barrier();
}

// ---------------------------------------------------------------------------
// pre-GEMM: C = A @ W^T + bias, bf16 MFMA, fp32 accum. 128x64, BK=32,
// 4 waves, depth-4 ring, counted vmcnt, chunk-XOR swizzle, XCD swizzle.
// ---------------------------------------------------------------------------
template <int TM, int TN>
__global__ __launch_bounds__(256) void gemm_pl(
    const unsigned short* __restrict__ A, const unsigned short* __restrict__ W,
    int N, int K, int GY,
    const float* __restrict__ p0, float* __restrict__ of,
    unsigned short* __restrict__ ob) {
  constexpr int FM = TM / 32, FN = TN / 32;
  constexpr int IA = TM / 64, IW = TN / 64;
  constexpr int LPT = IA + IW;
  __shared__ __align__(16) unsigned short As[4][TM * 32];
  __shared__ __align__(16) unsigned short Ws[4][TN * 32];

  const int t = threadIdx.x, lane = t & 63, wave = t >> 6;
  const int lr = lane & 15;
  const int q = gridDim.x >> 3;
  const int s = (blockIdx.x & 7) * q + (blockIdx.x >> 3);
  const int bm = (s / GY) * TM, bn = (s % GY) * TN;
  const int wr = (wave >> 1) * (TM / 2), wc = (wave & 1) * (TN / 2);

  f32x4 acc[FM][FN];
#pragma unroll
  for (int i = 0; i < FM; ++i)
#pragma unroll
    for (int j = 0; j < FN; ++j) acc[i][j] = (f32x4){0.f, 0.f, 0.f, 0.f};

  const unsigned short* agB =
      A + (long)(bm + wave * (TM / 4) + (lane >> 2)) * K +
      ((lane & 3) ^ ((lane >> 3) & 3)) * 8;
  const unsigned short* wgB =
      W + (long)(bn + wave * (TN / 4) + (lane >> 2)) * K +
      ((lane & 3) ^ ((lane >> 3) & 3)) * 8;

  auto STAGE = [&](int k0, int b) {
#pragma unroll
    for (int j = 0; j < IA; ++j)
      gl16(agB + k0 + (long)j * 16 * K, &As[b][(wave * (TM / 4) + j * 16) * 32]);
#pragma unroll
    for (int j = 0; j < IW; ++j)
      gl16(wgB + k0 + (long)j * 16 * K, &Ws[b][(wave * (TN / 4) + j * 16) * 32]);
  };

  auto COMPUTE = [&](int b) {
    bf16x8 af[FM], bg[FN];
    const int sw = ((lane >> 4) ^ ((lane >> 1) & 3)) * 8;
#pragma unroll
    for (int m = 0; m < FM; ++m)
      af[m] = *(const bf16x8*)&As[b][(wr + m * 16 + lr) * 32 + sw];
#pragma unroll
    for (int n = 0; n < FN; ++n)
      bg[n] = *(const bf16x8*)&Ws[b][(wc + n * 16 + lr) * 32 + sw];
    __builtin_amdgcn_s_setprio(1);
#pragma unroll
    for (int m = 0; m < FM; ++m)
#pragma unroll
      for (int n = 0; n < FN; ++n)
        acc[m][n] = __builtin_amdgcn_mfma_f32_16x16x32_bf16(af[m], bg[n],
                                                            acc[m][n], 0, 0, 0);
    __builtin_amdgcn_s_setprio(0);
  };

  const int NT = K >> 5;
  STAGE(0, 0);
  STAGE(32, 1);
  for (int tt = 0; tt < NT; ++tt) {
    if (tt + 2 < NT) {
      STAGE((tt + 2) << 5, (tt + 2) & 3);
      waitv<2 * LPT>();
    } else if (tt + 1 < NT) {
      waitv<LPT>();
    } else {
      waitv<0>();
    }
    __builtin_amdgcn_s_barrier();
    COMPUTE(tt & 3);
    __builtin_amdgcn_sched_barrier(0);
  }

  const int m0 = bm + wr + (lane >> 4) * 4;
  const int n0 = bn + wc + lr;
#pragma unroll
  for (int mi = 0; mi < FM; ++mi)
#pragma unroll
    for (int ni = 0; ni < FN; ++ni) {
      const int n = n0 + ni * 16;
#pragma unroll
      for (int r = 0; r < 4; ++r) {
        const int m = m0 + mi * 16 + r;
        float v = acc[mi][ni][r] + p0[n];
        of[(long)m * N + n] = v;
        ob[(long)m * N + n] = f2b(v);
      }
    }
}

// ---------------------------------------------------------------------------
// mamba5: 5 Mamba blocks fused, grid 256 x 512thr, 32 rows/block, h resident.
// SMEM carve (shorts):
//   XiL  [0,16384)      32KB  xi -> y (chunk-XOR swizzled)
//   SzL  [16384,32768)  32KB  silu(z)
//   Ring [32768,65536)  64KB  4 x 16KB slots (tile = 64rows x 128 shorts!)
//   HLr  [65536,73728)  16KB  h bf16
//   Dxl  [73728,78080)  8.5KB xdbl f32, stride 68
//   BCl  [78080,78144)  32 f32
//   Par  [78144,81216)  1536 f32: cb[0..511], dtb[512..1023], D[1024..1535]
// P1/P5: ring-4 depth-3, stage-AFTER-barrier (slot (tt+3)%4 = (tt-1)%4 whose
// reads completed before all waves reached barrier(tt)); waitv drains tile tt
// before the barrier. No global loads inside loops (conv tap3 folded into
// inwb at precast; cb/dtb/D staged to Par by waves 0-5, drained at tt=0).
// L=1 collapse: conv = tap3*xi+cb; scan -> y = xi*(dt*BC+D)*silu(z).
// ---------------------------------------------------------------------------
__global__ __launch_bounds__(512) void mamba5(
    const unsigned short* __restrict__ hb0, const float* __restrict__ h0,
    const unsigned short* __restrict__ inwb,
    const unsigned short* __restrict__ xwpb,
    const unsigned short* __restrict__ dtwpb,
    const unsigned short* __restrict__ owb,
    const float* __restrict__ conv_b, const float* __restrict__ dt_b,
    const float* __restrict__ Dp, float* __restrict__ hout) {
  __shared__ __align__(16) unsigned short SMEM[81216];
  unsigned short* XiL = SMEM;
  unsigned short* SzL = SMEM + 16384;
  unsigned short* Ring = SMEM + 32768;
  unsigned short* HLr = SMEM + 65536;
  float* Dxl = (float*)(SMEM + 73728);
  float* BCl = (float*)(SMEM + 78080);
  float* Par = (float*)(SMEM + 78144);

  const int t = threadIdx.x, lane = t & 63, w = t >> 6;
  const int lr = lane & 15, lg = lane >> 4;
  const int bm = blockIdx.x * 32;
  const int fm = w & 1, fn = w >> 1;   // wave frag coords (2 x 4)
  const int arow = fm * 16 + lr;       // A-frag LDS row
  const int br = fn * 16 + lr;         // B-frag tile-local row
  const int m0 = fm * 16 + lg * 4;     // C/D frag row base

  // ---- init: h bf16 -> HLr; fp32 residual -> regs ----
#pragma unroll
  for (int j = 0; j < 2; ++j) {
    const int i = w * 2 + j;
    const int row = 2 * i + (lane >> 5);
    const int c = (lane & 31) ^ (row & 7);
    gl16(hb0 + (long)(bm + row) * 256 + c * 8, HLr + i * 512);
  }
  float hres[4][4];
#pragma unroll
  for (int ng = 0; ng < 4; ++ng)
#pragma unroll
    for (int r = 0; r < 4; ++r)
      hres[ng][r] = h0[(long)(bm + m0 + r) * 256 + ng * 64 + fn * 16 + lr];
  waitv<0>();
  __builtin_amdgcn_s_barrier();

  for (int blk = 0; blk < 5; ++blk) {
    const unsigned short* inw = inwb + (long)blk * 1024 * 256;
    const unsigned short* xwp = xwpb + (long)blk * 64 * 512;
    const unsigned short* dtwp = dtwpb + (long)blk * 512 * 32;
    const unsigned short* ow = owb + (long)blk * 256 * 512;
    const float* cbv = conv_b + blk * 512;
    const float* dtbv = dt_b + blk * 512;
    const float* Dv = Dp + blk * 512;

    // ================= P1: xz = h @ in_w'^T (conv-folded) =================
    auto STAGE1 = [&](int tt, int slot) {
      const int nt = tt >> 1, kh = tt & 1;
#pragma unroll
      for (int j = 0; j < 2; ++j) {
        const int u = w * 2 + j;  // 16 gl16/tile, 4 rows (256B) each
        const int row = 4 * u + (lane >> 4);
        const int c = (lane & 15) ^ (row & 7);
        gl16(inw + (long)(nt * 64 + row) * 256 + kh * 128 + c * 8,
             Ring + slot * 8192 + u * 512);
      }
    };
    // params into Par (waves 0-5 only; drained with tile0 at tt=0)
    if (w < 6) {
      const float* ps = (w < 2) ? cbv + (w & 1) * 256
                      : (w < 4) ? dtbv + (w & 1) * 256
                                : Dv + (w & 1) * 256;
      gl16(ps + lane * 4, (unsigned short*)Par + w * 512);
    }
    STAGE1(0, 0); STAGE1(1, 1); STAGE1(2, 2);
    f32x4 acc1 = {0.f, 0.f, 0.f, 0.f};
    for (int tt = 0; tt < 32; ++tt) {
      if (tt + 2 < 32) waitv<4>();
      else if (tt + 1 < 32) waitv<2>();
      else waitv<0>();
      __builtin_amdgcn_s_barrier();
      if (tt + 3 < 32) STAGE1(tt + 3, (tt + 3) & 3);
      __builtin_amdgcn_sched_barrier(0);
      const int nt = tt >> 1, kh = tt & 1;
      const int c = nt * 64 + fn * 16 + lr;
      if (kh == 0) {
        const float cb0 = (c < 512) ? Par[c] : 0.f;  // LDS read (no vmcnt)
        acc1 = (f32x4){cb0, cb0, cb0, cb0};
      }
      const unsigned short* Bs = Ring + (tt & 3) * 8192;
      {
        bf16x8 af[4], bg[4];
#pragma unroll
        for (int kc = 0; kc < 4; ++kc) {
          af[kc] = *(const bf16x8*)
              &HLr[arow * 256 + ((((kh * 4 + kc) * 4 + lg) ^ (arow & 7)) * 8)];
          bg[kc] = *(const bf16x8*)
              &Bs[br * 128 + (((kc * 4 + lg) ^ (br & 7)) * 8)];
        }
        __builtin_amdgcn_s_setprio(1);
#pragma unroll
        for (int kc = 0; kc < 4; ++kc)
          acc1 = __builtin_amdgcn_mfma_f32_16x16x32_bf16(af[kc], bg[kc], acc1,
                                                         0, 0, 0);
        __builtin_amdgcn_s_setprio(0);
      }
      if (kh == 1) {
        if (c < 512) {
#pragma unroll
          for (int r = 0; r < 4; ++r) {
            const int row = m0 + r;
            XiL[row * 512 + (((c >> 3) ^ (row & 7)) * 8) + (c & 7)] =
                f2b(fsilu(acc1[r]));
          }
        } else {
#pragma unroll
          for (int r = 0; r < 4; ++r)
            SzL[(m0 + r) * 512 + (c - 512)] = f2b(fsilu(acc1[r]));
        }
      }
      __builtin_amdgcn_sched_barrier(0);
    }
    lgkm_bar();  // Xi/Sz visible; Ring reads retired

    // ====== P2: xdbl = xi @ xwp^T (xwp 64KB into Ring contiguous) ======
#pragma unroll
    for (int j = 0; j < 8; ++j) {
      const int i = w * 8 + j;  // 64 gl16, 1 row (1KB) each
      gl16(xwp + (long)i * 512 + (lane ^ (i & 7)) * 8, Ring + i * 512);
    }
    waitv<0>();
    __builtin_amdgcn_s_barrier();
    {
      f32x4 a2 = {0.f, 0.f, 0.f, 0.f};
      bf16x8 af, bg;
      __builtin_amdgcn_s_setprio(1);
#pragma unroll
      for (int kc = 0; kc < 16; ++kc) {
        af = *(const bf16x8*)
            &XiL[arow * 512 + (((kc * 4 + lg) ^ (arow & 7)) * 8)];
        bg = *(const bf16x8*)
            &Ring[br * 512 + (((kc * 4 + lg) ^ (br & 7)) * 8)];
        a2 = __builtin_amdgcn_mfma_f32_16x16x32_bf16(af, bg, a2, 0, 0, 0);
      }
      __builtin_amdgcn_s_setprio(0);
#pragma unroll
      for (int r = 0; r < 4; ++r) Dxl[(m0 + r) * 68 + fn * 16 + lr] = a2[r];
    }
    lgkm_bar();  // Dxl visible; Ring reads retired

    // ===== P4 prologue: dtwp [512x32]=32KB into Ring[0..16384); overlap
    // with BC + afdt prep =====
#pragma unroll
    for (int j = 0; j < 4; ++j) {
      const int u = w * 4 + j;  // 32 gl16, 16 rows (64B) each
      const int row = u * 16 + (lane >> 2);
      const int c = (lane & 3) ^ (row & 3);
      gl16(dtwp + (long)row * 32 + c * 8, Ring + u * 512);
    }
    if (t < 32) {
      float bc = 0.f;
      const float* dx = &Dxl[t * 68];
#pragma unroll
      for (int s2 = 0; s2 < 16; ++s2) bc += dx[16 + s2] * dx[32 + s2];
      BCl[t] = bc;
    }
    bf16x8 afdt;
    {
      // k 16..31 (Bm cols) multiply vs zero-padded dtwp rows: contribute 0
      const float* dx = &Dxl[arow * 68 + lg * 8];
#pragma unroll
      for (int e = 0; e < 8; ++e) afdt[e] = (short)f2b(dx[e]);
    }
    waitv<0>();
    lgkm_bar();  // dtwp + BCl visible

    // ===== P4: dt = softplus(xdbl[:,:16]@dtwp^T + dtb); y (barrier-free,
    // dtb/D from Par LDS, each thread owns disjoint (row,d) entries) =====
#pragma unroll
    for (int tt = 0; tt < 8; ++tt) {
      const int d = tt * 64 + fn * 16 + lr;
      bf16x8 bg = *(const bf16x8*)&Ring[d * 32 + ((lg ^ (d & 3)) * 8)];
      f32x4 da = __builtin_amdgcn_mfma_f32_16x16x32_bf16(
          afdt, bg, (f32x4){0.f, 0.f, 0.f, 0.f}, 0, 0, 0);
      const float dbv = Par[512 + d], dvv = Par[1024 + d];
#pragma unroll
      for (int r = 0; r < 4; ++r) {
        const int row = m0 + r;
        const float dtv = fsoftplus(da[r] + dbv);
        const int xoff = row * 512 + (((d >> 3) ^ (row & 7)) * 8) + (d & 7);
        const float y = b2f(XiL[xoff]) * (dtv * BCl[row] + dvv) *
                        b2f(SzL[row * 512 + d]);
        XiL[xoff] = f2b(y);  // y overwrites xi in place
      }
    }
    lgkm_bar();  // y visible; dtwp reads retired

    // ===== P5: h += y @ ow^T (16 tiles [64Nx128K], ring-4 depth-3) =====
    auto STAGE5 = [&](int tt, int slot) {
      const int ng = tt >> 2, kq = tt & 3;
#pragma unroll
      for (int j = 0; j < 2; ++j) {
        const int u = w * 2 + j;
        const int row = u * 4 + (lane >> 4);
        const int c = (lane & 15) ^ (row & 7);
        gl16(ow + (long)(ng * 64 + row) * 512 + kq * 128 + c * 8,
             Ring + slot * 8192 + u * 512);
      }
    };
    STAGE5(0, 0); STAGE5(1, 1); STAGE5(2, 2);
    f32x4 acc5 = {0.f, 0.f, 0.f, 0.f};
    for (int tt = 0; tt < 16; ++tt) {
      if (tt + 2 < 16) waitv<4>();
      else if (tt + 1 < 16) waitv<2>();
      else waitv<0>();
      __builtin_amdgcn_s_barrier();
      if (tt + 3 < 16) STAGE5(tt + 3, (tt + 3) & 3);
      __builtin_amdgcn_sched_barrier(0);
      const int ng = tt >> 2, kq = tt & 3;
      if (kq == 0) acc5 = (f32x4){0.f, 0.f, 0.f, 0.f};
      const unsigned short* Bs = Ring + (tt & 3) * 8192;
      {
        bf16x8 af[4], bg[4];
#pragma unroll
        for (int kc = 0; kc < 4; ++kc) {
          af[kc] = *(const bf16x8*)
              &XiL[arow * 512 + (((kq * 16 + kc * 4 + lg) ^ (arow & 7)) * 8)];
          bg[kc] = *(const bf16x8*)
              &Bs[br * 128 + (((kc * 4 + lg) ^ (br & 7)) * 8)];
        }
        __builtin_amdgcn_s_setprio(1);
#pragma unroll
        for (int kc = 0; kc < 4; ++kc)
          acc5 = __builtin_amdgcn_mfma_f32_16x16x32_bf16(af[kc], bg[kc], acc5,
                                                         0, 0, 0);
        __builtin_amdgcn_s_setprio(0);
      }
      if (kq == 3) {
        const int col = ng * 64 + fn * 16 + lr;
#pragma unroll
        for (int r = 0; r < 4; ++r) {
          const int row = m0 + r;
          const float v = acc5[r] + hres[ng][r];
          hres[ng][r] = v;
          HLr[row * 256 + (((col >> 3) ^ (row & 7)) * 8) + (col & 7)] = f2b(v);
        }
      }
      __builtin_amdgcn_sched_barrier(0);
    }
    lgkm_bar();  // new h visible for next blk's P1
  }

  // ---- final h fp32 write for LN+cls ----
#pragma unroll
  for (int ng = 0; ng < 4; ++ng)
#pragma unroll
    for (int r = 0; r < 4; ++r)
      hout[(long)(bm + m0 + r) * 256 + ng * 64 + fn * 16 + lr] = hres[ng][r];
}

// x fp32 -> bf16 streaming cast
__global__ __launch_bounds__(256) void castx(const float* __restrict__ s,
                                             unsigned short* __restrict__ d) {
  const int n4 = (8192 * 2048) / 4;
  for (int i = blockIdx.x * 256 + threadIdx.x; i < n4; i += gridDim.x * 256) {
    float4v v = ((const float4v*)s)[i];
    s16x4 o;
    o[0] = (short)f2b(v[0]); o[1] = (short)f2b(v[1]);
    o[2] = (short)f2b(v[2]); o[3] = (short)f2b(v[3]);
    ((s16x4*)d)[i] = o;
  }
}

// weight precast: W_pre -> bf16; in_w -> bf16 with conv tap3 folded into
// rows <512; out_w -> bf16; x_proj -> padded [64x512]; dt_w -> padded [512x32]
__global__ __launch_bounds__(256) void precast(
    const float* __restrict__ wpre, const float* __restrict__ inw,
    const float* __restrict__ ow, const float* __restrict__ xw,
    const float* __restrict__ dtw, const float* __restrict__ cw,
    unsigned short* __restrict__ wpreb, unsigned short* __restrict__ inwb,
    unsigned short* __restrict__ owb, unsigned short* __restrict__ xwpb,
    unsigned short* __restrict__ dtwpb) {
  const int S0 = 524288;         // 256*2048
  const int S1 = S0 + 1310720;   // + 5*1024*256
  const int S2 = S1 + 655360;    // + 5*256*512
  const int S3 = S2 + 163840;    // + 5*64*512
  const int S4 = S3 + 81920;     // + 5*512*32
  int i4 = (blockIdx.x * 256 + threadIdx.x) * 4;
  if (i4 >= S4) return;
  float4v v = {0.f, 0.f, 0.f, 0.f};
  unsigned short* dst;
  if (i4 < S0) {
    v = *(const float4v*)(wpre + i4);
    dst = wpreb + i4;
  } else if (i4 < S1) {
    int o = i4 - S0;
    v = *(const float4v*)(inw + o);
    int b = o >> 18, row = (o >> 8) & 1023;
    if (row < 512) {
      float c3 = cw[(b * 512 + row) * 4 + 3];
      v[0] *= c3; v[1] *= c3; v[2] *= c3; v[3] *= c3;
    }
    dst = inwb + o;
  } else if (i4 < S2) {
    int o = i4 - S1;
    v = *(const float4v*)(ow + o);
    dst = owb + o;
  } else if (i4 < S3) {
    int o = i4 - S2;
    dst = xwpb + o;
    int k = o & 511, j = (o >> 9) & 63, b = o >> 15;
    if (j < 48) v = *(const float4v*)(xw + ((long)(b * 48 + j)) * 512 + k);
  } else {
    int o = i4 - S3;
    dst = dtwpb + o;
    int k = o & 31, dd = o >> 5;
    if (k < 16) v = *(const float4v*)(dtw + (long)dd * 16 + k);
  }
  s16x4 sv;
  sv[0] = (short)f2b(v[0]); sv[1] = (short)f2b(v[1]);
  sv[2] = (short)f2b(v[2]); sv[3] = (short)f2b(v[3]);
  *(s16x4*)dst = sv;
}

// LayerNorm(256) + classifier (8 outputs). One wave per row.
__global__ __launch_bounds__(256) void final_ln_cls(
    const float* __restrict__ h, const float* __restrict__ g,
    const float* __restrict__ be, const float* __restrict__ Wc,
    const float* __restrict__ bc, float* __restrict__ out) {
  const int wave = threadIdx.x >> 6, lane = threadIdx.x & 63;
  const int row = blockIdx.x * 4 + wave;
  const float4v* hr = (const float4v*)(h + (long)row * 256);
  float4v v = hr[lane];
  float s = v[0] + v[1] + v[2] + v[3];
#pragma unroll
  for (int o = 32; o; o >>= 1) s += __shfl_xor(s, o);
  const float mu = s * (1.f / 256.f);
  float d0 = v[0] - mu, d1 = v[1] - mu, d2 = v[2] - mu, d3 = v[3] - mu;
  float qq = d0 * d0 + d1 * d1 + d2 * d2 + d3 * d3;
#pragma unroll
  for (int o = 32; o; o >>= 1) qq += __shfl_xor(qq, o);
  const float rs = rsqrtf(qq * (1.f / 256.f) + 1e-5f);
  const float4v gv = ((const float4v*)g)[lane];
  const float4v bv = ((const float4v*)be)[lane];
  float hn[4];
  hn[0] = d0 * rs * gv[0] + bv[0];
  hn[1] = d1 * rs * gv[1] + bv[1];
  hn[2] = d2 * rs * gv[2] + bv[2];
  hn[3] = d3 * rs * gv[3] + bv[3];
  float lg[8];
#pragma unroll
  for (int o = 0; o < 8; ++o) {
    const float4v wv = ((const float4v*)(Wc + o * 256))[lane];
    float p = hn[0] * wv[0] + hn[1] * wv[1] + hn[2] * wv[2] + hn[3] * wv[3];
#pragma unroll
    for (int x = 32; x; x >>= 1) p += __shfl_xor(p, x);
    lg[o] = p;
  }
  if (lane == 0) {
#pragma unroll
    for (int o = 0; o < 8; ++o) out[(long)row * 8 + o] = lg[o] + bc[o];
  }
}

extern "C" void kernel_launch(void* const* d_in, const int* in_sizes, int n_in,
                              void* d_out, int out_size, void* d_ws,
                              size_t ws_size, hipStream_t stream) {
  const float* x      = (const float*)d_in[0];
  const float* W_pre  = (const float*)d_in[1];
  const float* b_pre  = (const float*)d_in[2];
  const float* in_w   = (const float*)d_in[3];
  const float* conv_w = (const float*)d_in[4];
  const float* conv_b = (const float*)d_in[5];
  const float* x_w    = (const float*)d_in[6];
  const float* dt_w   = (const float*)d_in[7];
  const float* dt_b   = (const float*)d_in[8];
  // d_in[9] = A_log: dead (scan starts from h0=0 and L=1)
  const float* Dp     = (const float*)d_in[10];
  const float* out_w  = (const float*)d_in[11];
  const float* ln_g   = (const float*)d_in[12];
  const float* ln_b   = (const float*)d_in[13];
  const float* W_cls  = (const float*)d_in[14];
  const float* b_cls  = (const float*)d_in[15];
  float* out = (float*)d_out;

  char* w = (char*)d_ws;
  unsigned short* wpreb = (unsigned short*)w; w += 256 * 2048 * 2;
  unsigned short* inwb  = (unsigned short*)w; w += 5 * 1024 * 256 * 2;
  unsigned short* xwpb  = (unsigned short*)w; w += 5 * 64 * 512 * 2;
  unsigned short* owb   = (unsigned short*)w; w += 5 * 256 * 512 * 2;
  unsigned short* dtwpb = (unsigned short*)w; w += 5 * 512 * 32 * 2;
  float*          h     = (float*)w;          w += 8192 * 256 * 4;
  unsigned short* hb    = (unsigned short*)w; w += 8192 * 256 * 2;
  unsigned short* xb    = (unsigned short*)w; w += 8192 * 2048 * 2;

  precast<<<2672, 256, 0, stream>>>(W_pre, in_w, out_w, x_w, dt_w, conv_w,
                                    wpreb, inwb, owb, xwpb, dtwpb);
  castx<<<2048, 256, 0, stream>>>(x, xb);

  // h = x @ W_pre^T + b_pre  (fp32 of + bf16 ob)
  gemm_pl<128, 64><<<256, 256, 0, stream>>>(
      xb, wpreb, 256, 2048, 4, b_pre, h, hb);

  // all 5 Mamba blocks, one persistent kernel, h resident
  mamba5<<<256, 512, 0, stream>>>(hb, h, inwb, xwpb, dtwpb, owb,
                                  conv_b, dt_b, Dp, h);

  final_ln_cls<<<2048, 256, 0, stream>>>(h, ln_g, ln_b, W_cls, b_cls, out);
}